// Round 8
// baseline (555.828 us; speedup 1.0000x reference)
//
#include <hip/hip_runtime.h>
#include <math.h>

__device__ __forceinline__ float sigf(float v) { return 1.f / (1.f + __expf(-v)); }

__device__ __forceinline__ short f2bf(float f) {
  unsigned int u = __builtin_bit_cast(unsigned int, f);
  unsigned int r = (u + 0x7fffu + ((u >> 16) & 1u)) >> 16;
  return (short)r;
}
__device__ __forceinline__ float bf2f(short s) {
  unsigned int u = ((unsigned int)(unsigned short)s) << 16;
  return __builtin_bit_cast(float, u);
}

typedef short bf16x8 __attribute__((ext_vector_type(8)));
typedef float f32x4 __attribute__((ext_vector_type(4)));

// per-dir strides (elements)
#define ZB_STRIDE   19005440ll   // floats, 8192x2320
#define XCV_STRIDE  10485760ll   // shorts, 8192x1280
#define SBUF_STRIDE 16777216ll   // shorts, 64*32*8192
#define YB_STRIDE    8388608ll   // shorts, 8192x1024
#define DT_STRIDE     131072ll   // floats
#define PB_STRIDE       2048ll   // floats
#define WINT_STRIDE  1310720ll   // shorts, 2560x512 (padded)

__device__ __forceinline__ void async16(const short* g, short* l) {
  __builtin_amdgcn_global_load_lds(
      (const __attribute__((address_space(1))) unsigned int*)g,
      (__attribute__((address_space(3))) unsigned int*)l, 16, 0, 0);
}

// ============ 256x256 counted-vmcnt GEMM (T4): C[M,N] = A[M,K] @ Bt[N,K]^T ============
// 3-LDS-buffer rotation makes the counted pipeline provably race-free:
// tile t lives in buf t%3; iteration t stages tile t+2 into buf (t+2)%3,
// which was freed at the PREVIOUS iteration's end barrier (stage writes can
// never land on live data). Tile t+1 completion enforced by vmcnt(4) at
// iteration end (only this iteration's 4 loads outstanding) -> loads span a
// full iteration, never drained to 0 in the main loop (T4, +38-73% lever).
// One barrier per 32 MFMA (old 128^2: one vmcnt(0) drain per 16).
// XOR slot swizzle identical to the 128^2 kernel (same 64B row pitch).
// 96KB LDS -> 1 block/CU x 8 waves. Use only where grid >= ~256 blocks.
template<bool BIAS>
__global__ __launch_bounds__(512, 2) void gemm256_kernel(
    const short* __restrict__ A, const short* __restrict__ Bt,
    const float* __restrict__ bias, float* __restrict__ C,
    int M, int N, int K, int ldc,
    long long sAb, long long sBb, long long sCb)
{
  __shared__ short smA[3][256 * 32];
  __shared__ short smB[3][256 * 32];
  const int tid = threadIdx.x;
  const int w = tid >> 6;
  const int lane = tid & 63;
  const int m0 = blockIdx.x * 256;
  const int n0 = blockIdx.y * 256;
  const short* Ab = A + (size_t)blockIdx.z * sAb;
  const short* Bb = Bt + (size_t)blockIdx.z * sBb;
  float* Cb = C + (size_t)blockIdx.z * sCb;

  const int wm = w >> 2, wn = w & 3;       // wave grid 2(M) x 4(N); 128x64 out/wave
  const int NT = K >> 5;

  // stager: thread tid covers (row = tid>>2 [+128 for 2nd load], slot = tid&3)
  // pre-swizzled global slot so linear LDS dest + swizzled read match (m173)
  const int gs8 = (((tid & 3) ^ ((tid >> 3) & 3)) * 8);
  const int r0 = tid >> 2;
  const int lb = (w * 16) * 32;            // wave-uniform LDS base (shorts)
  const short* gA = Ab + (size_t)(m0 + r0) * K + gs8;
  const short* gB = Bb + (size_t)(n0 + r0) * K + gs8;

  auto STAGE_A = [&](int buf, int t) {
    async16(gA + t * 32, &smA[buf][lb]);
    async16(gA + (size_t)128 * K + t * 32, &smA[buf][lb + 128 * 32]);
  };
  auto STAGE_B = [&](int buf, int t) {
    async16(gB + t * 32, &smB[buf][lb]);
    async16(gB + (size_t)128 * K + t * 32, &smB[buf][lb + 128 * 32]);
  };

  f32x4 acc[8][4] = {};
  const int mcol = lane & 15;
  const int nq = (lane >> 4) * 4;
  const int rs8 = (((lane >> 4) ^ ((lane >> 1) & 3)) * 8);

  STAGE_A(0, 0); STAGE_B(0, 0);
  if (NT > 1) { STAGE_A(1, 1); STAGE_B(1, 1); }
  if (NT > 1) asm volatile("s_waitcnt vmcnt(4)" ::: "memory");   // tile0 landed
  else        asm volatile("s_waitcnt vmcnt(0)" ::: "memory");
  __builtin_amdgcn_s_barrier();

  int cur = 0;
  for (int t = 0; t < NT; ++t) {
    int buf2 = cur + 2; if (buf2 >= 3) buf2 -= 3;
    const short* sa = smA[cur];
    const short* sb = smB[cur];
    bf16x8 bfr[4], af[4];
#pragma unroll
    for (int nt = 0; nt < 4; nt++)
      bfr[nt] = *(bf16x8*)&sb[(wn * 64 + nt * 16 + mcol) * 32 + rs8];
#pragma unroll
    for (int mt = 0; mt < 4; mt++)
      af[mt] = *(bf16x8*)&sa[(wm * 128 + mt * 16 + mcol) * 32 + rs8];
    if (t + 2 < NT) STAGE_A(buf2, t + 2);
#pragma unroll
    for (int mt = 0; mt < 4; mt++)
#pragma unroll
      for (int nt = 0; nt < 4; nt++)
        acc[mt][nt] = __builtin_amdgcn_mfma_f32_16x16x32_bf16(bfr[nt], af[mt], acc[mt][nt], 0, 0, 0);
#pragma unroll
    for (int mt = 0; mt < 4; mt++)
      af[mt] = *(bf16x8*)&sa[(wm * 128 + 64 + mt * 16 + mcol) * 32 + rs8];
    if (t + 2 < NT) STAGE_B(buf2, t + 2);
#pragma unroll
    for (int mt = 0; mt < 4; mt++)
#pragma unroll
      for (int nt = 0; nt < 4; nt++)
        acc[4 + mt][nt] = __builtin_amdgcn_mfma_f32_16x16x32_bf16(bfr[nt], af[mt], acc[4 + mt][nt], 0, 0, 0);
    if (t + 1 < NT) {
      if (t + 2 < NT) asm volatile("s_waitcnt vmcnt(4)" ::: "memory");  // t+1 landed, t+2 in flight
      else            asm volatile("s_waitcnt vmcnt(0)" ::: "memory");  // tail drain
      __builtin_amdgcn_s_barrier();
    }
    cur = (cur + 1 == 3) ? 0 : cur + 1;
  }

  // epilogue: lane row = base+(lane&15); cols = base+(lane>>4)*4+[0..3]
#pragma unroll
  for (int mt = 0; mt < 8; mt++) {
    int row = m0 + wm * 128 + (mt >> 2) * 64 + (mt & 3) * 16 + mcol;
#pragma unroll
    for (int nt = 0; nt < 4; nt++) {
      int col = n0 + wn * 64 + nt * 16 + nq;
      if (col >= N) continue;   // N%16==0 -> whole quad in/out
      float4 v = make_float4(acc[mt][nt][0], acc[mt][nt][1], acc[mt][nt][2], acc[mt][nt][3]);
      if (BIAS) {
        float4 bv = *(const float4*)(bias + col);
        v.x += bv.x; v.y += bv.y; v.z += bv.z; v.w += bv.w;
      }
      *(float4*)(Cb + (size_t)row * ldc + col) = v;
    }
  }
}

// ============ bf16 MFMA GEMM 128^2 (2-phase): C[M,N] += A[M,K] @ Bt[N,K]^T ============
// Kept for small-N call sites (grid too small for the 512-thread kernel).
// W16: additionally emit a bf16 copy of C (fuses cast_kernel into Wp gemm).
template<bool BIAS, bool ACC, bool W16>
__global__ __launch_bounds__(256) void gemm16_kernel(
    const short* __restrict__ A, const short* __restrict__ Bt,
    const float* __restrict__ bias, float* __restrict__ C,
    int M, int N, int K, int ldc,
    long long sAb, long long sBb, long long sCb,
    short* __restrict__ C16)
{
  __shared__ short sm[2][2][128 * 32];   // [buf][A=0/B=1][row*32 + slot*8]
  const int tid = threadIdx.x;
  const int wave = tid >> 6;
  const int lane = tid & 63;
  const int m0 = blockIdx.x * 128;
  const int n0 = blockIdx.y * 128;
  const int bz = blockIdx.z;
  const short* Ab = A + (size_t)bz * sAb;
  const short* Bb = Bt + (size_t)bz * sBb;
  float* Cb = C + (size_t)bz * sCb;

  f32x4 acc[4][4] = {};

  const int isB = wave >> 1;
  const int half = wave & 1;
  const short* gsrc = isB ? Bb : Ab;
  const int tile_r0 = isB ? n0 : m0;
  const int lrow = lane >> 2;
  const int lk = (((lane & 3) ^ ((lane >> 3) & 3)) * 8);   // pre-swizzled global slot
  const short* gbase = gsrc + (size_t)(tile_r0 + half * 64 + lrow) * K + lk;
  short* lbase0 = &sm[0][isB][(half * 64) * 32];
  short* lbase1 = &sm[1][isB][(half * 64) * 32];

  const int wm = wave >> 1, wn = wave & 1;
  const int nt = K >> 5;

  auto STAGE = [&](int buf, int t) {
    const short* g0 = gbase + t * 32;
    short* l0 = buf ? lbase1 : lbase0;
#pragma unroll
    for (int c = 0; c < 4; c++)
      async16(g0 + (size_t)c * 16 * K, l0 + c * 512);
  };

  STAGE(0, 0);
  asm volatile("s_waitcnt vmcnt(0)" ::: "memory");
  __builtin_amdgcn_s_barrier();

  const int rs = (((lane >> 4) ^ ((lane >> 1) & 3)) * 8);
  int cur = 0;
  for (int t = 0; t < nt; ++t) {
    if (t + 1 < nt) STAGE(cur ^ 1, t + 1);
    const short* smA = &sm[cur][0][0];
    const short* smB = &sm[cur][1][0];
    bf16x8 af[4], bfr[4];
#pragma unroll
    for (int mt = 0; mt < 4; mt++)
      af[mt] = *(bf16x8*)&smA[(wm * 64 + mt * 16 + (lane & 15)) * 32 + rs];
#pragma unroll
    for (int nn = 0; nn < 4; nn++)
      bfr[nn] = *(bf16x8*)&smB[(wn * 64 + nn * 16 + (lane & 15)) * 32 + rs];
#pragma unroll
    for (int mt = 0; mt < 4; mt++)
#pragma unroll
      for (int nn = 0; nn < 4; nn++)
        acc[mt][nn] = __builtin_amdgcn_mfma_f32_16x16x32_bf16(bfr[nn], af[mt], acc[mt][nn], 0, 0, 0);
    asm volatile("s_waitcnt vmcnt(0)" ::: "memory");
    __builtin_amdgcn_s_barrier();
    cur ^= 1;
  }
  const int mcol = lane & 15;
  const int nq = (lane >> 4) * 4;
#pragma unroll
  for (int mt = 0; mt < 4; mt++) {
    int row = m0 + wm * 64 + mt * 16 + mcol;
#pragma unroll
    for (int nn = 0; nn < 4; nn++) {
      int col = n0 + wn * 64 + nn * 16 + nq;
      if (col >= N) continue;
      float4 v = make_float4(acc[mt][nn][0], acc[mt][nn][1], acc[mt][nn][2], acc[mt][nn][3]);
      float* cp = Cb + (size_t)row * ldc + col;
      if (BIAS) {
        float4 bv = *(const float4*)(bias + col);
        v.x += bv.x; v.y += bv.y; v.z += bv.z; v.w += bv.w;
      }
      if (ACC) {
        float4 ov = *(const float4*)cp;
        v.x += ov.x; v.y += ov.y; v.z += ov.z; v.w += ov.w;
      }
      *(float4*)cp = v;
      if (W16) {
        *(short4*)(C16 + (size_t)row * ldc + col) =
            make_short4(f2bf(v.x), f2bf(v.y), f2bf(v.z), f2bf(v.w));
      }
    }
  }
}

// ---- transpose+cast: W[K][N] fp32 -> Wt[Np][K] bf16 (zero pad rows >= N) ----
__global__ void tcast_kernel(const float* __restrict__ W, short* __restrict__ Wt,
                             int K, int N)
{
  __shared__ float tile[32][33];
  int n0 = blockIdx.x * 32, k0 = blockIdx.y * 32;
  int c = threadIdx.x & 31, r8 = threadIdx.x >> 5;
#pragma unroll
  for (int i = 0; i < 4; i++) {
    int r = r8 + i * 8;
    int n = n0 + c;
    tile[r][c] = (n < N) ? W[(size_t)(k0 + r) * N + n] : 0.f;
  }
  __syncthreads();
#pragma unroll
  for (int i = 0; i < 4; i++) {
    int r = r8 + i * 8;
    Wt[(size_t)(n0 + r) * K + k0 + c] = f2bf(tile[c][r]);
  }
}

// ---- dual-dir variant: blockIdx.z selects source weight + dest offset ----
__global__ void tcast2_kernel(const float* __restrict__ W0, const float* __restrict__ W1,
                              short* __restrict__ Wt, int K, int N, long long sWt)
{
  __shared__ float tile[32][33];
  const int dir = blockIdx.z;
  const float* W = dir ? W1 : W0;
  short* Wtd = Wt + (size_t)dir * sWt;
  int n0 = blockIdx.x * 32, k0 = blockIdx.y * 32;
  int c = threadIdx.x & 31, r8 = threadIdx.x >> 5;
#pragma unroll
  for (int i = 0; i < 4; i++) {
    int r = r8 + i * 8;
    int n = n0 + c;
    tile[r][c] = (n < N) ? W[(size_t)(k0 + r) * N + n] : 0.f;
  }
  __syncthreads();
#pragma unroll
  for (int i = 0; i < 4; i++) {
    int r = r8 + i * 8;
    Wtd[(size_t)(n0 + r) * K + k0 + c] = f2bf(tile[c][r]);
  }
}

// ---- gather+cast: Ag16[m][s*256+d] = x[b][s][t][d], m=b*2048+t ----
__global__ void gather_cast_kernel(const float* __restrict__ x, short* __restrict__ Ag)
{
  int idx = blockIdx.x * 256 + threadIdx.x;
  int m = idx / 192;
  int g = idx - m * 192;
  int k = g * 4;
  int s = k >> 8, d = k & 255;
  int b = m >> 11, t = m & 2047;
  float4 v = *(const float4*)(x + ((size_t)((b * 3 + s) * 2048 + t) << 8) + d);
  *(short4*)(Ag + (size_t)m * 768 + k) = make_short4(f2bf(v.x), f2bf(v.y), f2bf(v.z), f2bf(v.w));
}

// ---------------- LayerNorm over 512, in place + bf16 copy ----------------
__global__ void ln512_kernel(float* __restrict__ xio, const float* __restrict__ g,
                             const float* __restrict__ b, short* __restrict__ o16)
{
  const int row = blockIdx.x;
  const int lane = threadIdx.x;
  float* xr = xio + (size_t)row * 512;
  float4 v0 = *(float4*)(xr + lane * 4);
  float4 v1 = *(float4*)(xr + 256 + lane * 4);
  float sum = v0.x + v0.y + v0.z + v0.w + v1.x + v1.y + v1.z + v1.w;
#pragma unroll
  for (int o = 32; o >= 1; o >>= 1) sum += __shfl_xor(sum, o);
  const float mu = sum * (1.f / 512.f);
  float d[8] = {v0.x - mu, v0.y - mu, v0.z - mu, v0.w - mu,
                v1.x - mu, v1.y - mu, v1.z - mu, v1.w - mu};
  float vs = 0.f;
#pragma unroll
  for (int i = 0; i < 8; i++) vs += d[i] * d[i];
#pragma unroll
  for (int o = 32; o >= 1; o >>= 1) vs += __shfl_xor(vs, o);
  const float inv = rsqrtf(vs * (1.f / 512.f) + 1e-5f);
  float4 g0 = *(const float4*)(g + lane * 4);
  float4 g1 = *(const float4*)(g + 256 + lane * 4);
  float4 b0 = *(const float4*)(b + lane * 4);
  float4 b1 = *(const float4*)(b + 256 + lane * 4);
  v0.x = d[0] * inv * g0.x + b0.x; v0.y = d[1] * inv * g0.y + b0.y;
  v0.z = d[2] * inv * g0.z + b0.z; v0.w = d[3] * inv * g0.w + b0.w;
  v1.x = d[4] * inv * g1.x + b1.x; v1.y = d[5] * inv * g1.y + b1.y;
  v1.z = d[6] * inv * g1.z + b1.z; v1.w = d[7] * inv * g1.w + b1.w;
  *(float4*)(xr + lane * 4) = v0;
  *(float4*)(xr + 256 + lane * 4) = v1;
  short* orow = o16 + (size_t)row * 512;
  *(short4*)(orow + lane * 4) = make_short4(f2bf(v0.x), f2bf(v0.y), f2bf(v0.z), f2bf(v0.w));
  *(short4*)(orow + 256 + lane * 4) = make_short4(f2bf(v1.x), f2bf(v1.y), f2bf(v1.z), f2bf(v1.w));
}

// --------- dt = softplus(raw + dtb), logdA = -dt * exp(Alog); dual-dir ---------
__global__ void dtprep_kernel(const float* __restrict__ Z,
                              const float* __restrict__ dtb0, const float* __restrict__ dtb1,
                              const float* __restrict__ Alog0, const float* __restrict__ Alog1,
                              float* __restrict__ dtv, float* __restrict__ ldA)
{
  const int dir = blockIdx.y;
  const float* Zd = Z + (size_t)dir * ZB_STRIDE;
  const float* dtb = dir ? dtb1 : dtb0;
  const float* Alog = dir ? Alog1 : Alog0;
  float* dtvd = dtv + dir * DT_STRIDE;
  float* ldAd = ldA + dir * DT_STRIDE;
  int idx = blockIdx.x * 256 + threadIdx.x;
  int row = idx >> 4, hh = idx & 15;
  float raw = Zd[(size_t)row * 2320 + 2304 + hh] + dtb[hh];
  float dt = raw > 20.f ? raw : log1pf(expf(raw));
  dtvd[idx] = dt;
  ldAd[idx] = -dt * expf(Alog[hh]);
}

// ---- depthwise conv(4) + bias + silu, bf16 out; dual-dir ----
// Sliding-window time tiling: every Z element fetched exactly once.
__global__ void conv_kernel(const float* __restrict__ Z,
                            const float* __restrict__ cw0, const float* __restrict__ cw1,
                            const float* __restrict__ cb0, const float* __restrict__ cb1,
                            short* __restrict__ xcv)
{
  const int dir = blockIdx.z;
  const int t0 = blockIdx.x * 64;
  const int b = blockIdx.y / 5;
  const int chb = blockIdx.y % 5;
  const int c = chb * 256 + threadIdx.x;
  const float* convw = dir ? cw1 : cw0;
  const float* convb = dir ? cb1 : cb0;
  const float* Zd = Z + (size_t)dir * ZB_STRIDE + (size_t)(b * 2048) * 2320 + 1024 + c;
  short* xd = xcv + (size_t)dir * XCV_STRIDE + (size_t)(b * 2048) * 1280 + c;

  const float w0 = convw[c * 4 + 0], w1 = convw[c * 4 + 1];
  const float w2 = convw[c * 4 + 2], w3 = convw[c * 4 + 3];
  const float bias = convb[c];
  const int o = dir ? 0 : -3;

  float rr[4];
#pragma unroll
  for (int j = 0; j < 4; j++) {
    int pos = t0 + o + j;
    rr[j] = (pos >= 0 && pos < 2048) ? Zd[(size_t)pos * 2320] : 0.f;
  }
#pragma unroll 8
  for (int i = 0; i < 64; i++) {
    float a = bias;
    if (dir) { a += w0 * rr[3]; a += w1 * rr[2]; a += w2 * rr[1]; a += w3 * rr[0]; }
    else     { a += w0 * rr[0]; a += w1 * rr[1]; a += w2 * rr[2]; a += w3 * rr[3]; }
    xd[(size_t)(t0 + i) * 1280] = f2bf(a * sigf(a));
    rr[0] = rr[1]; rr[1] = rr[2]; rr[2] = rr[3];
    int pos = t0 + i + 1 + o + 3;
    rr[3] = (pos >= 0 && pos < 2048) ? Zd[(size_t)pos * 2320] : 0.f;
  }
}

// ============ chunked SSD scan, Lc=64, 32 chunks; dual-dir via blockIdx.z ============
__global__ __launch_bounds__(256) void chunk_state_kernel(
    const short* __restrict__ xcv_, const float* __restrict__ dtv_,
    const float* __restrict__ ldA_, short* __restrict__ Sbuf_,
    float* __restrict__ Pbuf_)
{
  __shared__ float sw[64];
  __shared__ short sXT[64 * 74];    // [p][s]
  __shared__ short sBw[128 * 74];   // [n][s], weight folded
  const int dir = blockIdx.z;
  const short* xcv = xcv_ + (size_t)dir * XCV_STRIDE;
  const float* dtv = dtv_ + dir * DT_STRIDE;
  const float* ldA = ldA_ + dir * DT_STRIDE;
  short* Sbuf = Sbuf_ + (size_t)dir * SBUF_STRIDE;
  float* Pbuf = Pbuf_ + dir * PB_STRIDE;
  const int bh = blockIdx.x, ck = blockIdx.y;
  const int b = bh >> 4, h = bh & 15;
  const int tid = threadIdx.x;
  const int wave = tid >> 6, lane = tid & 63;

  if (tid < 64) {
    int tg = ck * 64 + tid;
    int tt = dir ? 2047 - tg : tg;
    size_t r = (size_t)(b * 2048 + tt) * 16 + h;
    float v = ldA[r];
#pragma unroll
    for (int o = 1; o < 64; o <<= 1) { float u = __shfl_up(v, o); if (tid >= o) v += u; }
    float tot = __shfl(v, 63);
    sw[tid] = __expf(tot - v) * dtv[r];
    if (tid == 63) Pbuf[bh * 32 + ck] = __expf(tot);
  }
  __syncthreads();
  for (int i4 = tid; i4 < 512; i4 += 256) {
    int s = i4 >> 3, p0 = (i4 & 7) * 8;
    int tg = ck * 64 + s; int tt = dir ? 2047 - tg : tg;
    bf16x8 xv = *(const bf16x8*)(xcv + (size_t)(b * 2048 + tt) * 1280 + h * 64 + p0);
#pragma unroll
    for (int j = 0; j < 8; j++) sXT[(p0 + j) * 74 + s] = xv[j];
  }
  for (int i4 = tid; i4 < 1024; i4 += 256) {
    int s = i4 >> 4, n0 = (i4 & 15) * 8;
    int tg = ck * 64 + s; int tt = dir ? 2047 - tg : tg;
    bf16x8 bv = *(const bf16x8*)(xcv + (size_t)(b * 2048 + tt) * 1280 + 1024 + n0);
    float w = sw[s];
#pragma unroll
    for (int j = 0; j < 8; j++) sBw[(n0 + j) * 74 + s] = f2bf(w * bf2f(bv[j]));
  }
  __syncthreads();

  const int mcol = lane & 15, kgrp = (lane >> 4) * 8;
  bf16x8 af[2];
#pragma unroll
  for (int kk = 0; kk < 2; kk++)
    af[kk] = *(bf16x8*)&sXT[(wave * 16 + mcol) * 74 + kk * 32 + kgrp];
  f32x4 acc[8] = {};
#pragma unroll
  for (int j = 0; j < 8; j++)
#pragma unroll
    for (int kk = 0; kk < 2; kk++) {
      bf16x8 bf = *(bf16x8*)&sBw[(j * 16 + mcol) * 74 + kk * 32 + kgrp];
      acc[j] = __builtin_amdgcn_mfma_f32_16x16x32_bf16(bf, af[kk], acc[j], 0, 0, 0);
    }
  short* Sp = Sbuf + ((size_t)(bh * 32 + ck) << 13);
  const int p = wave * 16 + mcol;
  const int nq = (lane >> 4) * 4;
#pragma unroll
  for (int j = 0; j < 8; j++) {
    *(short4*)(Sp + p * 128 + j * 16 + nq) = make_short4(
        f2bf(acc[j][0]), f2bf(acc[j][1]), f2bf(acc[j][2]), f2bf(acc[j][3]));
  }
}

// chunk_scan: in place on bf16 S, fp32 accumulate. 2 elems/thread; dual-dir.
__global__ void chunk_scan_kernel(short* __restrict__ Sbuf, const float* __restrict__ Pbuf)
{
  int idx = blockIdx.x * 256 + threadIdx.x;
  int bhd = idx >> 12;
  int pr = idx & 4095;
  int dir = bhd >> 6, bh = bhd & 63;
  short* Sb = Sbuf + (size_t)dir * SBUF_STRIDE;
  const float* Pb = Pbuf + dir * PB_STRIDE;
  float h0 = 0.f, h1 = 0.f;
  for (int ck = 0; ck < 32; ck++) {
    size_t off = ((size_t)(bh * 32 + ck) << 13) + pr * 2;
    unsigned int u = *(const unsigned int*)(Sb + off);
    float s0 = bf2f((short)(u & 0xffff));
    float s1 = bf2f((short)(u >> 16));
    float P = Pb[bh * 32 + ck];
    unsigned int w = (unsigned int)(unsigned short)f2bf(h0) |
                     ((unsigned int)(unsigned short)f2bf(h1) << 16);
    *(unsigned int*)(Sb + off) = w;
    h0 = P * h0 + s0;
    h1 = P * h1 + s1;
  }
}

// ======== chunk_out (MFMA): y = P@X + exp(L_t)*(C@H^T) + Dh*x, bf16 out; dual-dir ========
__global__ __launch_bounds__(256) void chunk_out_kernel(
    const short* __restrict__ xcv_, const float* __restrict__ dtv_,
    const float* __restrict__ ldA_, const short* __restrict__ Sbuf_,
    const float* __restrict__ Dh0, const float* __restrict__ Dh1,
    short* __restrict__ y_)
{
  extern __shared__ short smem16[];
  short* sB  = smem16;            // [64][136]
  short* sXT = sB + 64 * 136;     // [64][74]
  short* sP  = sXT + 64 * 74;     // [64][74]
  float* sL  = (float*)(sP + 64 * 74);
  float* sdt = sL + 64;

  const int dir = blockIdx.z;
  const short* xcv = xcv_ + (size_t)dir * XCV_STRIDE;
  const float* dtv = dtv_ + dir * DT_STRIDE;
  const float* ldA = ldA_ + dir * DT_STRIDE;
  const short* Sbuf = Sbuf_ + (size_t)dir * SBUF_STRIDE;
  const float* Dh = dir ? Dh1 : Dh0;
  short* y = y_ + (size_t)dir * YB_STRIDE;

  const int bh = blockIdx.x, ck = blockIdx.y;
  const int b = bh >> 4, h = bh & 15;
  const int tid = threadIdx.x;
  const int wave = tid >> 6, lane = tid & 63;

  const int mcol = lane & 15;
  const int kgrp = (lane >> 4) * 8;
  const int trow = wave * 16 + mcol;
  const int sq = (lane >> 4) * 4;

  const int tgc = ck * 64 + trow;
  const int ttc = dir ? 2047 - tgc : tgc;
  const short* crow = xcv + (size_t)(b * 2048 + ttc) * 1280 + 1152;
  bf16x8 afC[4];
#pragma unroll
  for (int kk = 0; kk < 4; kk++)
    afC[kk] = *(const bf16x8*)(crow + kk * 32 + kgrp);

  if (tid < 64) {
    int tg = ck * 64 + tid;
    int tt = dir ? 2047 - tg : tg;
    size_t r = (size_t)(b * 2048 + tt) * 16 + h;
    float v = ldA[r];
#pragma unroll
    for (int o = 1; o < 64; o <<= 1) { float u = __shfl_up(v, o); if (tid >= o) v += u; }
    sL[tid] = v;
    sdt[tid] = dtv[r];
  }
  for (int i4 = tid; i4 < 1024; i4 += 256) {
    int t = i4 >> 4, c8 = (i4 & 15) * 8;
    int tg = ck * 64 + t; int tt = dir ? 2047 - tg : tg;
    const short* rp = xcv + (size_t)(b * 2048 + tt) * 1280;
    *(bf16x8*)&sB[t * 136 + c8] = *(const bf16x8*)(rp + 1024 + c8);
  }
  for (int i4 = tid; i4 < 512; i4 += 256) {
    int t = i4 >> 3, p0 = (i4 & 7) * 8;
    int tg = ck * 64 + t; int tt = dir ? 2047 - tg : tg;
    bf16x8 xv = *(const bf16x8*)(xcv + (size_t)(b * 2048 + tt) * 1280 + h * 64 + p0);
#pragma unroll
    for (int j = 0; j < 8; j++) sXT[(p0 + j) * 74 + t] = xv[j];
  }
  __syncthreads();

  f32x4 sacc[4] = {};
#pragma unroll
  for (int j = 0; j < 4; j++)
#pragma unroll
    for (int kk = 0; kk < 4; kk++) {
      bf16x8 bf = *(bf16x8*)&sB[(j * 16 + mcol) * 136 + kk * 32 + kgrp];
      sacc[j] = __builtin_amdgcn_mfma_f32_16x16x32_bf16(bf, afC[kk], sacc[j], 0, 0, 0);
    }

  const float Lt = sL[trow];
#pragma unroll
  for (int j = 0; j < 4; j++) {
    int s0 = j * 16 + sq;
    float vr[4];
#pragma unroll
    for (int r = 0; r < 4; r++) {
      int s = s0 + r;
      vr[r] = (trow >= s) ? sacc[j][r] * __expf(Lt - sL[s]) * sdt[s] : 0.f;
    }
    *(short4*)&sP[trow * 74 + s0] = make_short4(
        f2bf(vr[0]), f2bf(vr[1]), f2bf(vr[2]), f2bf(vr[3]));
  }
  // sP rows are per-wave-disjoint: intra-wave LDS ordering suffices.
  asm volatile("s_waitcnt lgkmcnt(0)" ::: "memory");
  __builtin_amdgcn_sched_barrier(0);

  bf16x8 afP[2];
#pragma unroll
  for (int kk = 0; kk < 2; kk++)
    afP[kk] = *(bf16x8*)&sP[trow * 74 + kk * 32 + kgrp];
  f32x4 yacc[4] = {};
#pragma unroll
  for (int j = 0; j < 4; j++)
#pragma unroll
    for (int kk = 0; kk < 2; kk++) {
      bf16x8 bf = *(bf16x8*)&sXT[(j * 16 + mcol) * 74 + kk * 32 + kgrp];
      yacc[j] = __builtin_amdgcn_mfma_f32_16x16x32_bf16(bf, afP[kk], yacc[j], 0, 0, 0);
    }
  const short* Hp = Sbuf + ((size_t)(bh * 32 + ck) << 13);
  f32x4 y2[4] = {};
#pragma unroll
  for (int j = 0; j < 4; j++)
#pragma unroll
    for (int kk = 0; kk < 4; kk++) {
      bf16x8 bf = *(const bf16x8*)(Hp + (j * 16 + mcol) * 128 + kk * 32 + kgrp);
      y2[j] = __builtin_amdgcn_mfma_f32_16x16x32_bf16(bf, afC[kk], y2[j], 0, 0, 0);
    }

  const float dh = Dh[h];
  const float eL = __expf(Lt);
  short* yrow = y + (size_t)(b * 2048 + ttc) * 1024 + h * 64;
#pragma unroll
  for (int j = 0; j < 4; j++) {
    int p0 = j * 16 + sq;
    short o[4];
#pragma unroll
    for (int r = 0; r < 4; r++) {
      float xv = bf2f(sXT[(p0 + r) * 74 + trow]);
      o[r] = f2bf(yacc[j][r] + eL * y2[j][r] + dh * xv);
    }
    *(short4*)(yrow + p0) = make_short4(o[0], o[1], o[2], o[3]);
  }
}

// ------ y16 = bf16(rmsnorm(y16 * silu(z)) * normw), in place; dual-dir ------
__global__ void rms_kernel(short* __restrict__ y_, const float* __restrict__ Z,
                           const float* __restrict__ nw0, const float* __restrict__ nw1)
{
  const int dir = blockIdx.y;
  const int row = blockIdx.x;
  const int lane = threadIdx.x;
  short* yr = y_ + (size_t)dir * YB_STRIDE + (size_t)row * 1024;
  const float* zr = Z + (size_t)dir * ZB_STRIDE + (size_t)row * 2320;
  const float* normw = dir ? nw1 : nw0;
  float vals[16];
  float ss = 0.f;
#pragma unroll
  for (int jj = 0; jj < 4; jj++) {
    int off = jj * 256 + lane * 4;
    short4 yv = *(short4*)(yr + off);
    float4 zv = *(const float4*)(zr + off);
    float a0 = bf2f(yv.x) * (zv.x * sigf(zv.x));
    float a1 = bf2f(yv.y) * (zv.y * sigf(zv.y));
    float a2 = bf2f(yv.z) * (zv.z * sigf(zv.z));
    float a3 = bf2f(yv.w) * (zv.w * sigf(zv.w));
    vals[jj * 4 + 0] = a0; vals[jj * 4 + 1] = a1;
    vals[jj * 4 + 2] = a2; vals[jj * 4 + 3] = a3;
    ss += a0 * a0 + a1 * a1 + a2 * a2 + a3 * a3;
  }
#pragma unroll
  for (int o = 32; o >= 1; o >>= 1) ss += __shfl_xor(ss, o);
  const float scale = rsqrtf(ss * (1.f / 1024.f) + 1e-5f);
#pragma unroll
  for (int jj = 0; jj < 4; jj++) {
    int off = jj * 256 + lane * 4;
    float4 nw = *(const float4*)(normw + off);
    *(short4*)(yr + off) = make_short4(
        f2bf(vals[jj * 4 + 0] * scale * nw.x), f2bf(vals[jj * 4 + 1] * scale * nw.y),
        f2bf(vals[jj * 4 + 2] * scale * nw.z), f2bf(vals[jj * 4 + 3] * scale * nw.w));
  }
}

// ---- ob16 = bf16((od0+od1) * silu(h)) over 8192x512 ----
__global__ void combine_kernel(const float* __restrict__ od0, const float* __restrict__ od1,
                               const float* __restrict__ h, short* __restrict__ ob)
{
  size_t idx = (size_t)blockIdx.x * 256 + threadIdx.x;
  float4 a = ((const float4*)od0)[idx];
  float4 bb = ((const float4*)od1)[idx];
  float4 g = ((const float4*)h)[idx];
  float4 o;
  o.x = (a.x + bb.x) * (g.x * sigf(g.x));
  o.y = (a.y + bb.y) * (g.y * sigf(g.y));
  o.z = (a.z + bb.z) * (g.z * sigf(g.z));
  o.w = (a.w + bb.w) * (g.w * sigf(g.w));
  *(short4*)(ob + idx * 4) = make_short4(f2bf(o.x), f2bf(o.y), f2bf(o.z), f2bf(o.w));
}

__global__ void lnshort_kernel(const float* __restrict__ v, const float* __restrict__ g,
                               const float* __restrict__ b, const float* __restrict__ shortcut,
                               float* __restrict__ out0, short* __restrict__ fn)
{
  const int row = blockIdx.x;
  const int lane = threadIdx.x;
  size_t base = (size_t)row * 256;
  float4 x = *(const float4*)(v + base + lane * 4);
  float sum = x.x + x.y + x.z + x.w;
#pragma unroll
  for (int o = 32; o >= 1; o >>= 1) sum += __shfl_xor(sum, o);
  const float mu = sum * (1.f / 256.f);
  float d[4] = {x.x - mu, x.y - mu, x.z - mu, x.w - mu};
  float vs = d[0] * d[0] + d[1] * d[1] + d[2] * d[2] + d[3] * d[3];
#pragma unroll
  for (int o = 32; o >= 1; o >>= 1) vs += __shfl_xor(vs, o);
  const float inv = rsqrtf(vs * (1.f / 256.f) + 1e-5f);
  float4 gg = *(const float4*)(g + lane * 4);
  float4 bb = *(const float4*)(b + lane * 4);
  float4 sc = *(const float4*)(shortcut + base + lane * 4);
  float4 o4;
  o4.x = d[0] * inv * gg.x + bb.x + sc.x;
  o4.y = d[1] * inv * gg.y + bb.y + sc.y;
  o4.z = d[2] * inv * gg.z + bb.z + sc.z;
  o4.w = d[3] * inv * gg.w + bb.w + sc.w;
  *(float4*)(out0 + base + lane * 4) = o4;
  float ns = o4.x * o4.x + o4.y * o4.y + o4.z * o4.z + o4.w * o4.w;
#pragma unroll
  for (int o = 32; o >= 1; o >>= 1) ns += __shfl_xor(ns, o);
  const float r = 1.f / fmaxf(sqrtf(ns), 1e-12f);
  *(short4*)(fn + base + lane * 4) =
      make_short4(f2bf(o4.x * r), f2bf(o4.y * r), f2bf(o4.z * r), f2bf(o4.w * r));
}

extern "C" void kernel_launch(void* const* d_in, const int* in_sizes, int n_in,
                              void* d_out, int out_size, void* d_ws, size_t ws_size,
                              hipStream_t stream)
{
  (void)in_sizes; (void)n_in; (void)out_size; (void)ws_size;
  const float* x        = (const float*)d_in[0];
  const float* Wp       = (const float*)d_in[1];
  const float* bp       = (const float*)d_in[2];
  const float* Wpre     = (const float*)d_in[3];
  const float* bpre     = (const float*)d_in[4];
  const float* lnpre_g  = (const float*)d_in[5];
  const float* lnpre_b  = (const float*)d_in[6];
  const float* Wpost    = (const float*)d_in[7];
  const float* bpost    = (const float*)d_in[8];
  const float* lnpost_g = (const float*)d_in[9];
  const float* lnpost_b = (const float*)d_in[10];
  const float* Win_f   = (const float*)d_in[11];
  const float* convw_f = (const float*)d_in[12];
  const float* convb_f = (const float*)d_in[13];
  const float* dtb_f   = (const float*)d_in[14];
  const float* Alog_f  = (const float*)d_in[15];
  const float* Dh_f    = (const float*)d_in[16];
  const float* normw_f = (const float*)d_in[17];
  const float* Wout_f  = (const float*)d_in[18];
  const float* Win_b   = (const float*)d_in[19];
  const float* convw_b = (const float*)d_in[20];
  const float* convb_b = (const float*)d_in[21];
  const float* dtb_b   = (const float*)d_in[22];
  const float* Alog_b  = (const float*)d_in[23];
  const float* Dh_b    = (const float*)d_in[24];
  const float* normw_b = (const float*)d_in[25];
  const float* Wout_b  = (const float*)d_in[26];

  // ---- workspace layout (floats; 75,497,472 fl = 288 MiB available) ----
  float* ws   = (float*)d_ws;
  float* Zb   = ws;                         // 2 x 19,005,440
  float* xcvr = Zb + 2 * 19005440;          // 10,485,760 (overlay region)
  float* xc   = xcvr + 10485760;            // 2,097,152
  float* hbuf = xc + 2097152;               // 4,194,304
  short* hb16 = (short*)(hbuf + 4194304);   // 2,097,152 fl
  float* yb16f= hbuf + 4194304 + 2097152;   // 8,388,608 fl (2 dirs x 8192x1024 sh)
  short* yb16 = (short*)yb16f;
  float* od   = yb16f + 8388608;            // 4,194,304
  float* dtv  = od + 4194304;               // 2 x 131,072
  float* ldA  = dtv + 262144;               // 2 x 131,072
  float* Pbuf = ldA + 262144;               // 2 x 2,048
  short* WinT = (short*)(Pbuf + 4096);      // 2 x 2560x512 sh = 1,310,720 fl (N-padded)
  short* WoutT= WinT + 2 * WINT_STRIDE;     // 2 x 512x1024 sh = 524,288 fl
  // end = 71,831,552 fl < 75,497,472 ok

  short* xcv16  = (short*)xcvr;                // 2 dirs x 8192x1280 sh (scan loop)
  short* Ag16   = (short*)xcvr;                // 8192x768 sh (until gather gemm)
  short* WpT    = (short*)(xcvr + 3145728);    // 256x768 sh
  short* xcb    = (short*)xcvr;                // 8192x256 sh (until pre gemm)
  short* WpreT  = (short*)(xcvr + 1048576);    // 512x256 sh
  short* ob16   = (short*)xcvr;                // 8192x512 sh (after xcv dead)
  short* WpostT = (short*)(xcvr + 2097152);    // 256x512 sh (past ob16)
  float* vbuf = yb16f;                         // after Wout gemms (yb16 dead)
  short* fn16 = (short*)(yb16f + 2097152);

  float* out0 = (float*)d_out;
  float* attn = out0 + 2097152;
  short* Sbuf16 = (short*)attn;                // 2 dirs x 64*32*8192 sh (dead before Wout)
  float* od1 = attn;                           // dir1 Wout output (attn written later)

  // ---- prologue ----
  tcast_kernel<<<dim3(8, 24), 256, 0, stream>>>(Wp, WpT, 768, 256);
  gather_cast_kernel<<<6144, 256, 0, stream>>>(x, Ag16);
  // Wp gemm writes fp32 xc (shortcut) AND bf16 xcb (fused cast)
  gemm16_kernel<true, false, true><<<dim3(64, 2), 256, 0, stream>>>(
      Ag16, WpT, bp, xc, 8192, 256, 768, 256, 0, 0, 0, xcb);
  tcast_kernel<<<dim3(16, 8), 256, 0, stream>>>(Wpre, WpreT, 256, 512);
  gemm16_kernel<true, false, false><<<dim3(64, 4), 256, 0, stream>>>(
      xcb, WpreT, bpre, hbuf, 8192, 512, 256, 512, 0, 0, 0, nullptr);
  ln512_kernel<<<8192, 64, 0, stream>>>(hbuf, lnpre_g, lnpre_b, hb16);

  // ---- both directions batched (blockIdx.z / blockIdx.y = dir) ----
  tcast2_kernel<<<dim3(80, 16, 2), 256, 0, stream>>>(Win_f, Win_b, WinT, 512, 2320, WINT_STRIDE);
  tcast2_kernel<<<dim3(16, 32, 2), 256, 0, stream>>>(Wout_f, Wout_b, WoutT, 1024, 512, 524288);
  gemm256_kernel<false><<<dim3(32, 10, 2), 512, 0, stream>>>(
      hb16, WinT, nullptr, Zb, 8192, 2320, 512, 2320, 0, WINT_STRIDE, ZB_STRIDE);
  dtprep_kernel<<<dim3(512, 2), 256, 0, stream>>>(Zb, dtb_f, dtb_b, Alog_f, Alog_b, dtv, ldA);
  conv_kernel<<<dim3(32, 20, 2), 256, 0, stream>>>(Zb, convw_f, convw_b, convb_f, convb_b, xcv16);
  chunk_state_kernel<<<dim3(64, 32, 2), 256, 0, stream>>>(xcv16, dtv, ldA, Sbuf16, Pbuf);
  chunk_scan_kernel<<<2048, 256, 0, stream>>>(Sbuf16, Pbuf);
  chunk_out_kernel<<<dim3(64, 32, 2), 256, 36864, stream>>>(xcv16, dtv, ldA, Sbuf16, Dh_f, Dh_b, yb16);
  rms_kernel<<<dim3(8192, 2), 64, 0, stream>>>(yb16, Zb, normw_f, normw_b);
  gemm16_kernel<false, false, false><<<dim3(64, 4), 256, 0, stream>>>(
      yb16, WoutT, nullptr, od, 8192, 512, 1024, 512, 0, 0, 0, nullptr);
  gemm16_kernel<false, false, false><<<dim3(64, 4), 256, 0, stream>>>(
      yb16 + YB_STRIDE, WoutT + 524288, nullptr, od1, 8192, 512, 1024, 512, 0, 0, 0, nullptr);

  // ---- epilogue ----
  combine_kernel<<<4096, 256, 0, stream>>>(od, od1, hbuf, ob16);
  tcast_kernel<<<dim3(8, 16), 256, 0, stream>>>(Wpost, WpostT, 512, 256);
  gemm16_kernel<true, false, false><<<dim3(64, 2), 256, 0, stream>>>(
      ob16, WpostT, bpost, vbuf, 8192, 256, 512, 256, 0, 0, 0, nullptr);
  lnshort_kernel<<<8192, 64, 0, stream>>>(vbuf, lnpost_g, lnpost_b, xc, out0, fn16);
  gemm256_kernel<false><<<dim3(8, 8, 4), 512, 0, stream>>>(
      fn16, fn16, nullptr, attn, 2048, 2048, 256, 2048,
      (long long)2048 * 256, (long long)2048 * 256, (long long)2048 * 2048);
}

// Round 9
// 548.449 us; speedup vs baseline: 1.0135x; 1.0135x over previous
//
#include <hip/hip_runtime.h>
#include <math.h>

__device__ __forceinline__ float sigf(float v) { return 1.f / (1.f + __expf(-v)); }

__device__ __forceinline__ short f2bf(float f) {
  unsigned int u = __builtin_bit_cast(unsigned int, f);
  unsigned int r = (u + 0x7fffu + ((u >> 16) & 1u)) >> 16;
  return (short)r;
}
__device__ __forceinline__ float bf2f(short s) {
  unsigned int u = ((unsigned int)(unsigned short)s) << 16;
  return __builtin_bit_cast(float, u);
}

typedef short bf16x8 __attribute__((ext_vector_type(8)));
typedef float f32x4 __attribute__((ext_vector_type(4)));

// per-dir strides (elements)
#define ZB_STRIDE   19005440ll   // floats, 8192x2320
#define XCV_STRIDE  10485760ll   // shorts, 8192x1280
#define SBUF_STRIDE 16777216ll   // shorts, 64*32*8192
#define YB_STRIDE    8388608ll   // shorts, 8192x1024
#define DT_STRIDE     131072ll   // floats
#define PB_STRIDE       2048ll   // floats
#define WINT_STRIDE  1310720ll   // shorts, 2560x512 (padded)

__device__ __forceinline__ void async16(const short* g, short* l) {
  __builtin_amdgcn_global_load_lds(
      (const __attribute__((address_space(1))) unsigned int*)g,
      (__attribute__((address_space(3))) unsigned int*)l, 16, 0, 0);
}

// ============ bf16 MFMA GEMM 128^2 (2-phase): C[M,N] += A[M,K] @ Bt[N,K]^T ============
// Round-2 schedule (2 LDS buffers / 32 KB -> 5 blocks/CU, stage-ahead with
// single vmcnt(0)+s_barrier per K-step) + zero-cost XOR slot swizzle.
// DO NOT deepen the pipeline: 3-buffer 128^2 (r3) AND counted-vmcnt 256^2
// (r8) both REGRESSED — occupancy loss (5->3 / 5->1 blocks/CU) outweighs
// explicit pipelining at these shapes. 2-phase + 5 blocks/CU is the ceiling
// for this structure (~550 TF); further requires the full 8-phase
// fine-interleave template, not a coarse approximation.
// W16: additionally emit a bf16 copy of C (fuses cast_kernel into Wp gemm).
template<bool BIAS, bool ACC, bool W16>
__global__ __launch_bounds__(256) void gemm16_kernel(
    const short* __restrict__ A, const short* __restrict__ Bt,
    const float* __restrict__ bias, float* __restrict__ C,
    int M, int N, int K, int ldc,
    long long sAb, long long sBb, long long sCb,
    short* __restrict__ C16)
{
  __shared__ short sm[2][2][128 * 32];   // [buf][A=0/B=1][row*32 + slot*8]
  const int tid = threadIdx.x;
  const int wave = tid >> 6;
  const int lane = tid & 63;
  const int m0 = blockIdx.x * 128;
  const int n0 = blockIdx.y * 128;
  const int bz = blockIdx.z;
  const short* Ab = A + (size_t)bz * sAb;
  const short* Bb = Bt + (size_t)bz * sBb;
  float* Cb = C + (size_t)bz * sCb;

  f32x4 acc[4][4] = {};

  const int isB = wave >> 1;
  const int half = wave & 1;
  const short* gsrc = isB ? Bb : Ab;
  const int tile_r0 = isB ? n0 : m0;
  const int lrow = lane >> 2;
  const int lk = (((lane & 3) ^ ((lane >> 3) & 3)) * 8);   // pre-swizzled global slot
  const short* gbase = gsrc + (size_t)(tile_r0 + half * 64 + lrow) * K + lk;
  short* lbase0 = &sm[0][isB][(half * 64) * 32];
  short* lbase1 = &sm[1][isB][(half * 64) * 32];

  const int wm = wave >> 1, wn = wave & 1;
  const int nt = K >> 5;

  auto STAGE = [&](int buf, int t) {
    const short* g0 = gbase + t * 32;
    short* l0 = buf ? lbase1 : lbase0;
#pragma unroll
    for (int c = 0; c < 4; c++)
      async16(g0 + (size_t)c * 16 * K, l0 + c * 512);
  };

  STAGE(0, 0);
  asm volatile("s_waitcnt vmcnt(0)" ::: "memory");
  __builtin_amdgcn_s_barrier();

  const int rs = (((lane >> 4) ^ ((lane >> 1) & 3)) * 8);
  int cur = 0;
  for (int t = 0; t < nt; ++t) {
    if (t + 1 < nt) STAGE(cur ^ 1, t + 1);
    const short* smA = &sm[cur][0][0];
    const short* smB = &sm[cur][1][0];
    bf16x8 af[4], bfr[4];
#pragma unroll
    for (int mt = 0; mt < 4; mt++)
      af[mt] = *(bf16x8*)&smA[(wm * 64 + mt * 16 + (lane & 15)) * 32 + rs];
#pragma unroll
    for (int nn = 0; nn < 4; nn++)
      bfr[nn] = *(bf16x8*)&smB[(wn * 64 + nn * 16 + (lane & 15)) * 32 + rs];
#pragma unroll
    for (int mt = 0; mt < 4; mt++)
#pragma unroll
      for (int nn = 0; nn < 4; nn++)
        acc[mt][nn] = __builtin_amdgcn_mfma_f32_16x16x32_bf16(bfr[nn], af[mt], acc[mt][nn], 0, 0, 0);
    asm volatile("s_waitcnt vmcnt(0)" ::: "memory");
    __builtin_amdgcn_s_barrier();
    cur ^= 1;
  }
  const int mcol = lane & 15;
  const int nq = (lane >> 4) * 4;
#pragma unroll
  for (int mt = 0; mt < 4; mt++) {
    int row = m0 + wm * 64 + mt * 16 + mcol;
#pragma unroll
    for (int nn = 0; nn < 4; nn++) {
      int col = n0 + wn * 64 + nn * 16 + nq;
      if (col >= N) continue;
      float4 v = make_float4(acc[mt][nn][0], acc[mt][nn][1], acc[mt][nn][2], acc[mt][nn][3]);
      float* cp = Cb + (size_t)row * ldc + col;
      if (BIAS) {
        float4 bv = *(const float4*)(bias + col);
        v.x += bv.x; v.y += bv.y; v.z += bv.z; v.w += bv.w;
      }
      if (ACC) {
        float4 ov = *(const float4*)cp;
        v.x += ov.x; v.y += ov.y; v.z += ov.z; v.w += ov.w;
      }
      *(float4*)cp = v;
      if (W16) {
        *(short4*)(C16 + (size_t)row * ldc + col) =
            make_short4(f2bf(v.x), f2bf(v.y), f2bf(v.z), f2bf(v.w));
      }
    }
  }
}

// ---- transpose+cast: W[K][N] fp32 -> Wt[Np][K] bf16 (zero pad rows >= N) ----
__global__ void tcast_kernel(const float* __restrict__ W, short* __restrict__ Wt,
                             int K, int N)
{
  __shared__ float tile[32][33];
  int n0 = blockIdx.x * 32, k0 = blockIdx.y * 32;
  int c = threadIdx.x & 31, r8 = threadIdx.x >> 5;
#pragma unroll
  for (int i = 0; i < 4; i++) {
    int r = r8 + i * 8;
    int n = n0 + c;
    tile[r][c] = (n < N) ? W[(size_t)(k0 + r) * N + n] : 0.f;
  }
  __syncthreads();
#pragma unroll
  for (int i = 0; i < 4; i++) {
    int r = r8 + i * 8;
    Wt[(size_t)(n0 + r) * K + k0 + c] = f2bf(tile[c][r]);
  }
}

// ---- dual-dir variant: blockIdx.z selects source weight + dest offset ----
__global__ void tcast2_kernel(const float* __restrict__ W0, const float* __restrict__ W1,
                              short* __restrict__ Wt, int K, int N, long long sWt)
{
  __shared__ float tile[32][33];
  const int dir = blockIdx.z;
  const float* W = dir ? W1 : W0;
  short* Wtd = Wt + (size_t)dir * sWt;
  int n0 = blockIdx.x * 32, k0 = blockIdx.y * 32;
  int c = threadIdx.x & 31, r8 = threadIdx.x >> 5;
#pragma unroll
  for (int i = 0; i < 4; i++) {
    int r = r8 + i * 8;
    int n = n0 + c;
    tile[r][c] = (n < N) ? W[(size_t)(k0 + r) * N + n] : 0.f;
  }
  __syncthreads();
#pragma unroll
  for (int i = 0; i < 4; i++) {
    int r = r8 + i * 8;
    Wtd[(size_t)(n0 + r) * K + k0 + c] = f2bf(tile[c][r]);
  }
}

// ---- gather+cast: Ag16[m][s*256+d] = x[b][s][t][d], m=b*2048+t ----
__global__ void gather_cast_kernel(const float* __restrict__ x, short* __restrict__ Ag)
{
  int idx = blockIdx.x * 256 + threadIdx.x;
  int m = idx / 192;
  int g = idx - m * 192;
  int k = g * 4;
  int s = k >> 8, d = k & 255;
  int b = m >> 11, t = m & 2047;
  float4 v = *(const float4*)(x + ((size_t)((b * 3 + s) * 2048 + t) << 8) + d);
  *(short4*)(Ag + (size_t)m * 768 + k) = make_short4(f2bf(v.x), f2bf(v.y), f2bf(v.z), f2bf(v.w));
}

// ---------------- LayerNorm over 512, in place + bf16 copy ----------------
__global__ void ln512_kernel(float* __restrict__ xio, const float* __restrict__ g,
                             const float* __restrict__ b, short* __restrict__ o16)
{
  const int row = blockIdx.x;
  const int lane = threadIdx.x;
  float* xr = xio + (size_t)row * 512;
  float4 v0 = *(float4*)(xr + lane * 4);
  float4 v1 = *(float4*)(xr + 256 + lane * 4);
  float sum = v0.x + v0.y + v0.z + v0.w + v1.x + v1.y + v1.z + v1.w;
#pragma unroll
  for (int o = 32; o >= 1; o >>= 1) sum += __shfl_xor(sum, o);
  const float mu = sum * (1.f / 512.f);
  float d[8] = {v0.x - mu, v0.y - mu, v0.z - mu, v0.w - mu,
                v1.x - mu, v1.y - mu, v1.z - mu, v1.w - mu};
  float vs = 0.f;
#pragma unroll
  for (int i = 0; i < 8; i++) vs += d[i] * d[i];
#pragma unroll
  for (int o = 32; o >= 1; o >>= 1) vs += __shfl_xor(vs, o);
  const float inv = rsqrtf(vs * (1.f / 512.f) + 1e-5f);
  float4 g0 = *(const float4*)(g + lane * 4);
  float4 g1 = *(const float4*)(g + 256 + lane * 4);
  float4 b0 = *(const float4*)(b + lane * 4);
  float4 b1 = *(const float4*)(b + 256 + lane * 4);
  v0.x = d[0] * inv * g0.x + b0.x; v0.y = d[1] * inv * g0.y + b0.y;
  v0.z = d[2] * inv * g0.z + b0.z; v0.w = d[3] * inv * g0.w + b0.w;
  v1.x = d[4] * inv * g1.x + b1.x; v1.y = d[5] * inv * g1.y + b1.y;
  v1.z = d[6] * inv * g1.z + b1.z; v1.w = d[7] * inv * g1.w + b1.w;
  *(float4*)(xr + lane * 4) = v0;
  *(float4*)(xr + 256 + lane * 4) = v1;
  short* orow = o16 + (size_t)row * 512;
  *(short4*)(orow + lane * 4) = make_short4(f2bf(v0.x), f2bf(v0.y), f2bf(v0.z), f2bf(v0.w));
  *(short4*)(orow + 256 + lane * 4) = make_short4(f2bf(v1.x), f2bf(v1.y), f2bf(v1.z), f2bf(v1.w));
}

// --------- dt = softplus(raw + dtb), logdA = -dt * exp(Alog); dual-dir ---------
__global__ void dtprep_kernel(const float* __restrict__ Z,
                              const float* __restrict__ dtb0, const float* __restrict__ dtb1,
                              const float* __restrict__ Alog0, const float* __restrict__ Alog1,
                              float* __restrict__ dtv, float* __restrict__ ldA)
{
  const int dir = blockIdx.y;
  const float* Zd = Z + (size_t)dir * ZB_STRIDE;
  const float* dtb = dir ? dtb1 : dtb0;
  const float* Alog = dir ? Alog1 : Alog0;
  float* dtvd = dtv + dir * DT_STRIDE;
  float* ldAd = ldA + dir * DT_STRIDE;
  int idx = blockIdx.x * 256 + threadIdx.x;
  int row = idx >> 4, hh = idx & 15;
  float raw = Zd[(size_t)row * 2320 + 2304 + hh] + dtb[hh];
  float dt = raw > 20.f ? raw : log1pf(expf(raw));
  dtvd[idx] = dt;
  ldAd[idx] = -dt * expf(Alog[hh]);
}

// ---- depthwise conv(4) + bias + silu, bf16 out; dual-dir ----
// Sliding-window time tiling: every Z element fetched exactly once.
__global__ void conv_kernel(const float* __restrict__ Z,
                            const float* __restrict__ cw0, const float* __restrict__ cw1,
                            const float* __restrict__ cb0, const float* __restrict__ cb1,
                            short* __restrict__ xcv)
{
  const int dir = blockIdx.z;
  const int t0 = blockIdx.x * 64;
  const int b = blockIdx.y / 5;
  const int chb = blockIdx.y % 5;
  const int c = chb * 256 + threadIdx.x;
  const float* convw = dir ? cw1 : cw0;
  const float* convb = dir ? cb1 : cb0;
  const float* Zd = Z + (size_t)dir * ZB_STRIDE + (size_t)(b * 2048) * 2320 + 1024 + c;
  short* xd = xcv + (size_t)dir * XCV_STRIDE + (size_t)(b * 2048) * 1280 + c;

  const float w0 = convw[c * 4 + 0], w1 = convw[c * 4 + 1];
  const float w2 = convw[c * 4 + 2], w3 = convw[c * 4 + 3];
  const float bias = convb[c];
  const int o = dir ? 0 : -3;

  float rr[4];
#pragma unroll
  for (int j = 0; j < 4; j++) {
    int pos = t0 + o + j;
    rr[j] = (pos >= 0 && pos < 2048) ? Zd[(size_t)pos * 2320] : 0.f;
  }
#pragma unroll 8
  for (int i = 0; i < 64; i++) {
    float a = bias;
    if (dir) { a += w0 * rr[3]; a += w1 * rr[2]; a += w2 * rr[1]; a += w3 * rr[0]; }
    else     { a += w0 * rr[0]; a += w1 * rr[1]; a += w2 * rr[2]; a += w3 * rr[3]; }
    xd[(size_t)(t0 + i) * 1280] = f2bf(a * sigf(a));
    rr[0] = rr[1]; rr[1] = rr[2]; rr[2] = rr[3];
    int pos = t0 + i + 1 + o + 3;
    rr[3] = (pos >= 0 && pos < 2048) ? Zd[(size_t)pos * 2320] : 0.f;
  }
}

// ============ chunked SSD scan, Lc=64, 32 chunks; dual-dir via blockIdx.z ============
__global__ __launch_bounds__(256) void chunk_state_kernel(
    const short* __restrict__ xcv_, const float* __restrict__ dtv_,
    const float* __restrict__ ldA_, short* __restrict__ Sbuf_,
    float* __restrict__ Pbuf_)
{
  __shared__ float sw[64];
  __shared__ short sXT[64 * 74];    // [p][s]
  __shared__ short sBw[128 * 74];   // [n][s], weight folded
  const int dir = blockIdx.z;
  const short* xcv = xcv_ + (size_t)dir * XCV_STRIDE;
  const float* dtv = dtv_ + dir * DT_STRIDE;
  const float* ldA = ldA_ + dir * DT_STRIDE;
  short* Sbuf = Sbuf_ + (size_t)dir * SBUF_STRIDE;
  float* Pbuf = Pbuf_ + dir * PB_STRIDE;
  const int bh = blockIdx.x, ck = blockIdx.y;
  const int b = bh >> 4, h = bh & 15;
  const int tid = threadIdx.x;
  const int wave = tid >> 6, lane = tid & 63;

  if (tid < 64) {
    int tg = ck * 64 + tid;
    int tt = dir ? 2047 - tg : tg;
    size_t r = (size_t)(b * 2048 + tt) * 16 + h;
    float v = ldA[r];
#pragma unroll
    for (int o = 1; o < 64; o <<= 1) { float u = __shfl_up(v, o); if (tid >= o) v += u; }
    float tot = __shfl(v, 63);
    sw[tid] = __expf(tot - v) * dtv[r];
    if (tid == 63) Pbuf[bh * 32 + ck] = __expf(tot);
  }
  __syncthreads();
  for (int i4 = tid; i4 < 512; i4 += 256) {
    int s = i4 >> 3, p0 = (i4 & 7) * 8;
    int tg = ck * 64 + s; int tt = dir ? 2047 - tg : tg;
    bf16x8 xv = *(const bf16x8*)(xcv + (size_t)(b * 2048 + tt) * 1280 + h * 64 + p0);
#pragma unroll
    for (int j = 0; j < 8; j++) sXT[(p0 + j) * 74 + s] = xv[j];
  }
  for (int i4 = tid; i4 < 1024; i4 += 256) {
    int s = i4 >> 4, n0 = (i4 & 15) * 8;
    int tg = ck * 64 + s; int tt = dir ? 2047 - tg : tg;
    bf16x8 bv = *(const bf16x8*)(xcv + (size_t)(b * 2048 + tt) * 1280 + 1024 + n0);
    float w = sw[s];
#pragma unroll
    for (int j = 0; j < 8; j++) sBw[(n0 + j) * 74 + s] = f2bf(w * bf2f(bv[j]));
  }
  __syncthreads();

  const int mcol = lane & 15, kgrp = (lane >> 4) * 8;
  bf16x8 af[2];
#pragma unroll
  for (int kk = 0; kk < 2; kk++)
    af[kk] = *(bf16x8*)&sXT[(wave * 16 + mcol) * 74 + kk * 32 + kgrp];
  f32x4 acc[8] = {};
#pragma unroll
  for (int j = 0; j < 8; j++)
#pragma unroll
    for (int kk = 0; kk < 2; kk++) {
      bf16x8 bf = *(bf16x8*)&sBw[(j * 16 + mcol) * 74 + kk * 32 + kgrp];
      acc[j] = __builtin_amdgcn_mfma_f32_16x16x32_bf16(bf, af[kk], acc[j], 0, 0, 0);
    }
  short* Sp = Sbuf + ((size_t)(bh * 32 + ck) << 13);
  const int p = wave * 16 + mcol;
  const int nq = (lane >> 4) * 4;
#pragma unroll
  for (int j = 0; j < 8; j++) {
    *(short4*)(Sp + p * 128 + j * 16 + nq) = make_short4(
        f2bf(acc[j][0]), f2bf(acc[j][1]), f2bf(acc[j][2]), f2bf(acc[j][3]));
  }
}

// chunk_scan: in place on bf16 S, fp32 accumulate. 2 elems/thread; dual-dir.
__global__ void chunk_scan_kernel(short* __restrict__ Sbuf, const float* __restrict__ Pbuf)
{
  int idx = blockIdx.x * 256 + threadIdx.x;
  int bhd = idx >> 12;
  int pr = idx & 4095;
  int dir = bhd >> 6, bh = bhd & 63;
  short* Sb = Sbuf + (size_t)dir * SBUF_STRIDE;
  const float* Pb = Pbuf + dir * PB_STRIDE;
  float h0 = 0.f, h1 = 0.f;
  for (int ck = 0; ck < 32; ck++) {
    size_t off = ((size_t)(bh * 32 + ck) << 13) + pr * 2;
    unsigned int u = *(const unsigned int*)(Sb + off);
    float s0 = bf2f((short)(u & 0xffff));
    float s1 = bf2f((short)(u >> 16));
    float P = Pb[bh * 32 + ck];
    unsigned int w = (unsigned int)(unsigned short)f2bf(h0) |
                     ((unsigned int)(unsigned short)f2bf(h1) << 16);
    *(unsigned int*)(Sb + off) = w;
    h0 = P * h0 + s0;
    h1 = P * h1 + s1;
  }
}

// ======== chunk_out (MFMA): y = P@X + exp(L_t)*(C@H^T) + Dh*x, bf16 out; dual-dir ========
__global__ __launch_bounds__(256) void chunk_out_kernel(
    const short* __restrict__ xcv_, const float* __restrict__ dtv_,
    const float* __restrict__ ldA_, const short* __restrict__ Sbuf_,
    const float* __restrict__ Dh0, const float* __restrict__ Dh1,
    short* __restrict__ y_)
{
  extern __shared__ short smem16[];
  short* sB  = smem16;            // [64][136]
  short* sXT = sB + 64 * 136;     // [64][74]
  short* sP  = sXT + 64 * 74;     // [64][74]
  float* sL  = (float*)(sP + 64 * 74);
  float* sdt = sL + 64;

  const int dir = blockIdx.z;
  const short* xcv = xcv_ + (size_t)dir * XCV_STRIDE;
  const float* dtv = dtv_ + dir * DT_STRIDE;
  const float* ldA = ldA_ + dir * DT_STRIDE;
  const short* Sbuf = Sbuf_ + (size_t)dir * SBUF_STRIDE;
  const float* Dh = dir ? Dh1 : Dh0;
  short* y = y_ + (size_t)dir * YB_STRIDE;

  const int bh = blockIdx.x, ck = blockIdx.y;
  const int b = bh >> 4, h = bh & 15;
  const int tid = threadIdx.x;
  const int wave = tid >> 6, lane = tid & 63;

  const int mcol = lane & 15;
  const int kgrp = (lane >> 4) * 8;
  const int trow = wave * 16 + mcol;
  const int sq = (lane >> 4) * 4;

  const int tgc = ck * 64 + trow;
  const int ttc = dir ? 2047 - tgc : tgc;
  const short* crow = xcv + (size_t)(b * 2048 + ttc) * 1280 + 1152;
  bf16x8 afC[4];
#pragma unroll
  for (int kk = 0; kk < 4; kk++)
    afC[kk] = *(const bf16x8*)(crow + kk * 32 + kgrp);

  if (tid < 64) {
    int tg = ck * 64 + tid;
    int tt = dir ? 2047 - tg : tg;
    size_t r = (size_t)(b * 2048 + tt) * 16 + h;
    float v = ldA[r];
#pragma unroll
    for (int o = 1; o < 64; o <<= 1) { float u = __shfl_up(v, o); if (tid >= o) v += u; }
    sL[tid] = v;
    sdt[tid] = dtv[r];
  }
  for (int i4 = tid; i4 < 1024; i4 += 256) {
    int t = i4 >> 4, c8 = (i4 & 15) * 8;
    int tg = ck * 64 + t; int tt = dir ? 2047 - tg : tg;
    const short* rp = xcv + (size_t)(b * 2048 + tt) * 1280;
    *(bf16x8*)&sB[t * 136 + c8] = *(const bf16x8*)(rp + 1024 + c8);
  }
  for (int i4 = tid; i4 < 512; i4 += 256) {
    int t = i4 >> 3, p0 = (i4 & 7) * 8;
    int tg = ck * 64 + t; int tt = dir ? 2047 - tg : tg;
    bf16x8 xv = *(const bf16x8*)(xcv + (size_t)(b * 2048 + tt) * 1280 + h * 64 + p0);
#pragma unroll
    for (int j = 0; j < 8; j++) sXT[(p0 + j) * 74 + t] = xv[j];
  }
  __syncthreads();

  f32x4 sacc[4] = {};
#pragma unroll
  for (int j = 0; j < 4; j++)
#pragma unroll
    for (int kk = 0; kk < 4; kk++) {
      bf16x8 bf = *(bf16x8*)&sB[(j * 16 + mcol) * 136 + kk * 32 + kgrp];
      sacc[j] = __builtin_amdgcn_mfma_f32_16x16x32_bf16(bf, afC[kk], sacc[j], 0, 0, 0);
    }

  const float Lt = sL[trow];
#pragma unroll
  for (int j = 0; j < 4; j++) {
    int s0 = j * 16 + sq;
    float vr[4];
#pragma unroll
    for (int r = 0; r < 4; r++) {
      int s = s0 + r;
      vr[r] = (trow >= s) ? sacc[j][r] * __expf(Lt - sL[s]) * sdt[s] : 0.f;
    }
    *(short4*)&sP[trow * 74 + s0] = make_short4(
        f2bf(vr[0]), f2bf(vr[1]), f2bf(vr[2]), f2bf(vr[3]));
  }
  // sP rows are per-wave-disjoint: intra-wave LDS ordering suffices.
  asm volatile("s_waitcnt lgkmcnt(0)" ::: "memory");
  __builtin_amdgcn_sched_barrier(0);

  bf16x8 afP[2];
#pragma unroll
  for (int kk = 0; kk < 2; kk++)
    afP[kk] = *(bf16x8*)&sP[trow * 74 + kk * 32 + kgrp];
  f32x4 yacc[4] = {};
#pragma unroll
  for (int j = 0; j < 4; j++)
#pragma unroll
    for (int kk = 0; kk < 2; kk++) {
      bf16x8 bf = *(bf16x8*)&sXT[(j * 16 + mcol) * 74 + kk * 32 + kgrp];
      yacc[j] = __builtin_amdgcn_mfma_f32_16x16x32_bf16(bf, afP[kk], yacc[j], 0, 0, 0);
    }
  const short* Hp = Sbuf + ((size_t)(bh * 32 + ck) << 13);
  f32x4 y2[4] = {};
#pragma unroll
  for (int j = 0; j < 4; j++)
#pragma unroll
    for (int kk = 0; kk < 4; kk++) {
      bf16x8 bf = *(const bf16x8*)(Hp + (j * 16 + mcol) * 128 + kk * 32 + kgrp);
      y2[j] = __builtin_amdgcn_mfma_f32_16x16x32_bf16(bf, afC[kk], y2[j], 0, 0, 0);
    }

  const float dh = Dh[h];
  const float eL = __expf(Lt);
  short* yrow = y + (size_t)(b * 2048 + ttc) * 1024 + h * 64;
#pragma unroll
  for (int j = 0; j < 4; j++) {
    int p0 = j * 16 + sq;
    short o[4];
#pragma unroll
    for (int r = 0; r < 4; r++) {
      float xv = bf2f(sXT[(p0 + r) * 74 + trow]);
      o[r] = f2bf(yacc[j][r] + eL * y2[j][r] + dh * xv);
    }
    *(short4*)(yrow + p0) = make_short4(o[0], o[1], o[2], o[3]);
  }
}

// ------ y16 = bf16(rmsnorm(y16 * silu(z)) * normw), in place; dual-dir ------
__global__ void rms_kernel(short* __restrict__ y_, const float* __restrict__ Z,
                           const float* __restrict__ nw0, const float* __restrict__ nw1)
{
  const int dir = blockIdx.y;
  const int row = blockIdx.x;
  const int lane = threadIdx.x;
  short* yr = y_ + (size_t)dir * YB_STRIDE + (size_t)row * 1024;
  const float* zr = Z + (size_t)dir * ZB_STRIDE + (size_t)row * 2320;
  const float* normw = dir ? nw1 : nw0;
  float vals[16];
  float ss = 0.f;
#pragma unroll
  for (int jj = 0; jj < 4; jj++) {
    int off = jj * 256 + lane * 4;
    short4 yv = *(short4*)(yr + off);
    float4 zv = *(const float4*)(zr + off);
    float a0 = bf2f(yv.x) * (zv.x * sigf(zv.x));
    float a1 = bf2f(yv.y) * (zv.y * sigf(zv.y));
    float a2 = bf2f(yv.z) * (zv.z * sigf(zv.z));
    float a3 = bf2f(yv.w) * (zv.w * sigf(zv.w));
    vals[jj * 4 + 0] = a0; vals[jj * 4 + 1] = a1;
    vals[jj * 4 + 2] = a2; vals[jj * 4 + 3] = a3;
    ss += a0 * a0 + a1 * a1 + a2 * a2 + a3 * a3;
  }
#pragma unroll
  for (int o = 32; o >= 1; o >>= 1) ss += __shfl_xor(ss, o);
  const float scale = rsqrtf(ss * (1.f / 1024.f) + 1e-5f);
#pragma unroll
  for (int jj = 0; jj < 4; jj++) {
    int off = jj * 256 + lane * 4;
    float4 nw = *(const float4*)(normw + off);
    *(short4*)(yr + off) = make_short4(
        f2bf(vals[jj * 4 + 0] * scale * nw.x), f2bf(vals[jj * 4 + 1] * scale * nw.y),
        f2bf(vals[jj * 4 + 2] * scale * nw.z), f2bf(vals[jj * 4 + 3] * scale * nw.w));
  }
}

// ---- ob16 = bf16((od0+od1) * silu(h)) over 8192x512 ----
__global__ void combine_kernel(const float* __restrict__ od0, const float* __restrict__ od1,
                               const float* __restrict__ h, short* __restrict__ ob)
{
  size_t idx = (size_t)blockIdx.x * 256 + threadIdx.x;
  float4 a = ((const float4*)od0)[idx];
  float4 bb = ((const float4*)od1)[idx];
  float4 g = ((const float4*)h)[idx];
  float4 o;
  o.x = (a.x + bb.x) * (g.x * sigf(g.x));
  o.y = (a.y + bb.y) * (g.y * sigf(g.y));
  o.z = (a.z + bb.z) * (g.z * sigf(g.z));
  o.w = (a.w + bb.w) * (g.w * sigf(g.w));
  *(short4*)(ob + idx * 4) = make_short4(f2bf(o.x), f2bf(o.y), f2bf(o.z), f2bf(o.w));
}

__global__ void lnshort_kernel(const float* __restrict__ v, const float* __restrict__ g,
                               const float* __restrict__ b, const float* __restrict__ shortcut,
                               float* __restrict__ out0, short* __restrict__ fn)
{
  const int row = blockIdx.x;
  const int lane = threadIdx.x;
  size_t base = (size_t)row * 256;
  float4 x = *(const float4*)(v + base + lane * 4);
  float sum = x.x + x.y + x.z + x.w;
#pragma unroll
  for (int o = 32; o >= 1; o >>= 1) sum += __shfl_xor(sum, o);
  const float mu = sum * (1.f / 256.f);
  float d[4] = {x.x - mu, x.y - mu, x.z - mu, x.w - mu};
  float vs = d[0] * d[0] + d[1] * d[1] + d[2] * d[2] + d[3] * d[3];
#pragma unroll
  for (int o = 32; o >= 1; o >>= 1) vs += __shfl_xor(vs, o);
  const float inv = rsqrtf(vs * (1.f / 256.f) + 1e-5f);
  float4 gg = *(const float4*)(g + lane * 4);
  float4 bb = *(const float4*)(b + lane * 4);
  float4 sc = *(const float4*)(shortcut + base + lane * 4);
  float4 o4;
  o4.x = d[0] * inv * gg.x + bb.x + sc.x;
  o4.y = d[1] * inv * gg.y + bb.y + sc.y;
  o4.z = d[2] * inv * gg.z + bb.z + sc.z;
  o4.w = d[3] * inv * gg.w + bb.w + sc.w;
  *(float4*)(out0 + base + lane * 4) = o4;
  float ns = o4.x * o4.x + o4.y * o4.y + o4.z * o4.z + o4.w * o4.w;
#pragma unroll
  for (int o = 32; o >= 1; o >>= 1) ns += __shfl_xor(ns, o);
  const float r = 1.f / fmaxf(sqrtf(ns), 1e-12f);
  *(short4*)(fn + base + lane * 4) =
      make_short4(f2bf(o4.x * r), f2bf(o4.y * r), f2bf(o4.z * r), f2bf(o4.w * r));
}

extern "C" void kernel_launch(void* const* d_in, const int* in_sizes, int n_in,
                              void* d_out, int out_size, void* d_ws, size_t ws_size,
                              hipStream_t stream)
{
  (void)in_sizes; (void)n_in; (void)out_size; (void)ws_size;
  const float* x        = (const float*)d_in[0];
  const float* Wp       = (const float*)d_in[1];
  const float* bp       = (const float*)d_in[2];
  const float* Wpre     = (const float*)d_in[3];
  const float* bpre     = (const float*)d_in[4];
  const float* lnpre_g  = (const float*)d_in[5];
  const float* lnpre_b  = (const float*)d_in[6];
  const float* Wpost    = (const float*)d_in[7];
  const float* bpost    = (const float*)d_in[8];
  const float* lnpost_g = (const float*)d_in[9];
  const float* lnpost_b = (const float*)d_in[10];
  const float* Win_f   = (const float*)d_in[11];
  const float* convw_f = (const float*)d_in[12];
  const float* convb_f = (const float*)d_in[13];
  const float* dtb_f   = (const float*)d_in[14];
  const float* Alog_f  = (const float*)d_in[15];
  const float* Dh_f    = (const float*)d_in[16];
  const float* normw_f = (const float*)d_in[17];
  const float* Wout_f  = (const float*)d_in[18];
  const float* Win_b   = (const float*)d_in[19];
  const float* convw_b = (const float*)d_in[20];
  const float* convb_b = (const float*)d_in[21];
  const float* dtb_b   = (const float*)d_in[22];
  const float* Alog_b  = (const float*)d_in[23];
  const float* Dh_b    = (const float*)d_in[24];
  const float* normw_b = (const float*)d_in[25];
  const float* Wout_b  = (const float*)d_in[26];

  // ---- workspace layout (floats; 75,497,472 fl = 288 MiB available) ----
  float* ws   = (float*)d_ws;
  float* Zb   = ws;                         // 2 x 19,005,440
  float* xcvr = Zb + 2 * 19005440;          // 10,485,760 (overlay region)
  float* xc   = xcvr + 10485760;            // 2,097,152
  float* hbuf = xc + 2097152;               // 4,194,304
  short* hb16 = (short*)(hbuf + 4194304);   // 2,097,152 fl
  float* yb16f= hbuf + 4194304 + 2097152;   // 8,388,608 fl (2 dirs x 8192x1024 sh)
  short* yb16 = (short*)yb16f;
  float* od   = yb16f + 8388608;            // 4,194,304
  float* dtv  = od + 4194304;               // 2 x 131,072
  float* ldA  = dtv + 262144;               // 2 x 131,072
  float* Pbuf = ldA + 262144;               // 2 x 2,048
  short* WinT = (short*)(Pbuf + 4096);      // 2 x 2560x512 sh = 1,310,720 fl (N-padded)
  short* WoutT= WinT + 2 * WINT_STRIDE;     // 2 x 512x1024 sh = 524,288 fl
  // end = 71,831,552 fl < 75,497,472 ok

  short* xcv16  = (short*)xcvr;                // 2 dirs x 8192x1280 sh (scan loop)
  short* Ag16   = (short*)xcvr;                // 8192x768 sh (until gather gemm)
  short* WpT    = (short*)(xcvr + 3145728);    // 256x768 sh
  short* xcb    = (short*)xcvr;                // 8192x256 sh (until pre gemm)
  short* WpreT  = (short*)(xcvr + 1048576);    // 512x256 sh
  short* ob16   = (short*)xcvr;                // 8192x512 sh (after xcv dead)
  short* WpostT = (short*)(xcvr + 2097152);    // 256x512 sh (past ob16)
  float* vbuf = yb16f;                         // after Wout gemms (yb16 dead)
  short* fn16 = (short*)(yb16f + 2097152);

  float* out0 = (float*)d_out;
  float* attn = out0 + 2097152;
  short* Sbuf16 = (short*)attn;                // 2 dirs x 64*32*8192 sh (dead before Wout)
  float* od1 = attn;                           // dir1 Wout output (attn written later)

  // ---- prologue ----
  tcast_kernel<<<dim3(8, 24), 256, 0, stream>>>(Wp, WpT, 768, 256);
  gather_cast_kernel<<<6144, 256, 0, stream>>>(x, Ag16);
  // Wp gemm writes fp32 xc (shortcut) AND bf16 xcb (fused cast)
  gemm16_kernel<true, false, true><<<dim3(64, 2), 256, 0, stream>>>(
      Ag16, WpT, bp, xc, 8192, 256, 768, 256, 0, 0, 0, xcb);
  tcast_kernel<<<dim3(16, 8), 256, 0, stream>>>(Wpre, WpreT, 256, 512);
  gemm16_kernel<true, false, false><<<dim3(64, 4), 256, 0, stream>>>(
      xcb, WpreT, bpre, hbuf, 8192, 512, 256, 512, 0, 0, 0, nullptr);
  ln512_kernel<<<8192, 64, 0, stream>>>(hbuf, lnpre_g, lnpre_b, hb16);

  // ---- both directions batched (blockIdx.z / blockIdx.y = dir) ----
  tcast2_kernel<<<dim3(80, 16, 2), 256, 0, stream>>>(Win_f, Win_b, WinT, 512, 2320, WINT_STRIDE);
  tcast2_kernel<<<dim3(16, 32, 2), 256, 0, stream>>>(Wout_f, Wout_b, WoutT, 1024, 512, 524288);
  gemm16_kernel<false, false, false><<<dim3(64, 19, 2), 256, 0, stream>>>(
      hb16, WinT, nullptr, Zb, 8192, 2320, 512, 2320, 0, WINT_STRIDE, ZB_STRIDE, nullptr);
  dtprep_kernel<<<dim3(512, 2), 256, 0, stream>>>(Zb, dtb_f, dtb_b, Alog_f, Alog_b, dtv, ldA);
  conv_kernel<<<dim3(32, 20, 2), 256, 0, stream>>>(Zb, convw_f, convw_b, convb_f, convb_b, xcv16);
  chunk_state_kernel<<<dim3(64, 32, 2), 256, 0, stream>>>(xcv16, dtv, ldA, Sbuf16, Pbuf);
  chunk_scan_kernel<<<2048, 256, 0, stream>>>(Sbuf16, Pbuf);
  chunk_out_kernel<<<dim3(64, 32, 2), 256, 36864, stream>>>(xcv16, dtv, ldA, Sbuf16, Dh_f, Dh_b, yb16);
  rms_kernel<<<dim3(8192, 2), 64, 0, stream>>>(yb16, Zb, normw_f, normw_b);
  gemm16_kernel<false, false, false><<<dim3(64, 4), 256, 0, stream>>>(
      yb16, WoutT, nullptr, od, 8192, 512, 1024, 512, 0, 0, 0, nullptr);
  gemm16_kernel<false, false, false><<<dim3(64, 4), 256, 0, stream>>>(
      yb16 + YB_STRIDE, WoutT + 524288, nullptr, od1, 8192, 512, 1024, 512, 0, 0, 0, nullptr);

  // ---- epilogue ----
  combine_kernel<<<4096, 256, 0, stream>>>(od, od1, hbuf, ob16);
  tcast_kernel<<<dim3(8, 16), 256, 0, stream>>>(Wpost, WpostT, 512, 256);
  gemm16_kernel<true, false, false><<<dim3(64, 2), 256, 0, stream>>>(
      ob16, WpostT, bpost, vbuf, 8192, 256, 512, 256, 0, 0, 0, nullptr);
  lnshort_kernel<<<8192, 64, 0, stream>>>(vbuf, lnpost_g, lnpost_b, xc, out0, fn16);
  gemm16_kernel<false, false, false><<<dim3(16, 16, 4), 256, 0, stream>>>(
      fn16, fn16, nullptr, attn, 2048, 2048, 256, 2048,
      (long long)2048 * 256, (long long)2048 * 256, (long long)2048 * 2048, nullptr);
}

// Round 10
// 530.683 us; speedup vs baseline: 1.0474x; 1.0335x over previous
//
#include <hip/hip_runtime.h>
#include <math.h>

__device__ __forceinline__ float sigf(float v) { return 1.f / (1.f + __expf(-v)); }

__device__ __forceinline__ short f2bf(float f) {
  unsigned int u = __builtin_bit_cast(unsigned int, f);
  unsigned int r = (u + 0x7fffu + ((u >> 16) & 1u)) >> 16;
  return (short)r;
}
__device__ __forceinline__ float bf2f(short s) {
  unsigned int u = ((unsigned int)(unsigned short)s) << 16;
  return __builtin_bit_cast(float, u);
}

typedef short bf16x8 __attribute__((ext_vector_type(8)));
typedef float f32x4 __attribute__((ext_vector_type(4)));

// per-dir strides (elements)
#define ZB_STRIDE   19005440ll   // floats, 8192x2320
#define XCV_STRIDE  10485760ll   // shorts, 8192x1280
#define SBUF_STRIDE 16777216ll   // shorts, 64*32*8192
#define YB_STRIDE    8388608ll   // shorts, 8192x1024
#define DT_STRIDE     131072ll   // floats
#define PB_STRIDE       2048ll   // floats
#define WINT_STRIDE  1310720ll   // shorts, 2560x512 (padded)

__device__ __forceinline__ void async16(const short* g, short* l) {
  __builtin_amdgcn_global_load_lds(
      (const __attribute__((address_space(1))) unsigned int*)g,
      (__attribute__((address_space(3))) unsigned int*)l, 16, 0, 0);
}

// ============ bf16 MFMA GEMM 128^2 (2-phase): C[M,N] += A[M,K] @ Bt[N,K]^T ============
// Round-2 schedule (2 LDS buffers / 32 KB -> 5 blocks/CU, stage-ahead with
// single vmcnt(0)+s_barrier per K-step) + zero-cost XOR slot swizzle.
// DO NOT deepen the pipeline: 3-buffer 128^2 (r3) AND counted-vmcnt 256^2
// (r8) both REGRESSED — occupancy loss outweighs explicit pipelining here.
// W16: also emit a bf16 copy of C (fuses cast_kernel into Wp gemm).
// SYM (A==Bt, symmetric output): grid.x is a LINEAR upper-triangle tile
// index; off-diagonal tiles mirror-store C[col][row] (bit-identical value —
// same K-order fp32 sum). Mirror stores coalesce to 64B segments (16 lanes
// share consecutive `row`). Compute drops 256 -> 136 tiles (-47%).
template<bool BIAS, bool ACC, bool W16, bool SYM>
__global__ __launch_bounds__(256) void gemm16_kernel(
    const short* __restrict__ A, const short* __restrict__ Bt,
    const float* __restrict__ bias, float* __restrict__ C,
    int M, int N, int K, int ldc,
    long long sAb, long long sBb, long long sCb,
    short* __restrict__ C16)
{
  __shared__ short sm[2][2][128 * 32];   // [buf][A=0/B=1][row*32 + slot*8]
  const int tid = threadIdx.x;
  const int wave = tid >> 6;
  const int lane = tid & 63;
  int bx, by;
  if (SYM) {
    int j = blockIdx.x;
    by = (int)((sqrtf(8.f * j + 1.f) - 1.f) * 0.5f);
    while ((by + 1) * (by + 2) / 2 <= j) by++;
    while (by * (by + 1) / 2 > j) by--;
    bx = j - by * (by + 1) / 2;          // bx <= by
  } else {
    bx = blockIdx.x; by = blockIdx.y;
  }
  const int m0 = bx * 128;
  const int n0 = by * 128;
  const int bz = blockIdx.z;
  const short* Ab = A + (size_t)bz * sAb;
  const short* Bb = Bt + (size_t)bz * sBb;
  float* Cb = C + (size_t)bz * sCb;

  f32x4 acc[4][4] = {};

  const int isB = wave >> 1;
  const int half = wave & 1;
  const short* gsrc = isB ? Bb : Ab;
  const int tile_r0 = isB ? n0 : m0;
  const int lrow = lane >> 2;
  const int lk = (((lane & 3) ^ ((lane >> 3) & 3)) * 8);   // pre-swizzled global slot
  const short* gbase = gsrc + (size_t)(tile_r0 + half * 64 + lrow) * K + lk;
  short* lbase0 = &sm[0][isB][(half * 64) * 32];
  short* lbase1 = &sm[1][isB][(half * 64) * 32];

  const int wm = wave >> 1, wn = wave & 1;
  const int nt = K >> 5;

  auto STAGE = [&](int buf, int t) {
    const short* g0 = gbase + t * 32;
    short* l0 = buf ? lbase1 : lbase0;
#pragma unroll
    for (int c = 0; c < 4; c++)
      async16(g0 + (size_t)c * 16 * K, l0 + c * 512);
  };

  STAGE(0, 0);
  asm volatile("s_waitcnt vmcnt(0)" ::: "memory");
  __builtin_amdgcn_s_barrier();

  const int rs = (((lane >> 4) ^ ((lane >> 1) & 3)) * 8);
  int cur = 0;
  for (int t = 0; t < nt; ++t) {
    if (t + 1 < nt) STAGE(cur ^ 1, t + 1);
    const short* smA = &sm[cur][0][0];
    const short* smB = &sm[cur][1][0];
    bf16x8 af[4], bfr[4];
#pragma unroll
    for (int mt = 0; mt < 4; mt++)
      af[mt] = *(bf16x8*)&smA[(wm * 64 + mt * 16 + (lane & 15)) * 32 + rs];
#pragma unroll
    for (int nn = 0; nn < 4; nn++)
      bfr[nn] = *(bf16x8*)&smB[(wn * 64 + nn * 16 + (lane & 15)) * 32 + rs];
#pragma unroll
    for (int mt = 0; mt < 4; mt++)
#pragma unroll
      for (int nn = 0; nn < 4; nn++)
        acc[mt][nn] = __builtin_amdgcn_mfma_f32_16x16x32_bf16(bfr[nn], af[mt], acc[mt][nn], 0, 0, 0);
    asm volatile("s_waitcnt vmcnt(0)" ::: "memory");
    __builtin_amdgcn_s_barrier();
    cur ^= 1;
  }
  const int mcol = lane & 15;
  const int nq = (lane >> 4) * 4;
#pragma unroll
  for (int mt = 0; mt < 4; mt++) {
    int row = m0 + wm * 64 + mt * 16 + mcol;
#pragma unroll
    for (int nn = 0; nn < 4; nn++) {
      int col = n0 + wn * 64 + nn * 16 + nq;
      if (col >= N) continue;
      float4 v = make_float4(acc[mt][nn][0], acc[mt][nn][1], acc[mt][nn][2], acc[mt][nn][3]);
      float* cp = Cb + (size_t)row * ldc + col;
      if (BIAS) {
        float4 bv = *(const float4*)(bias + col);
        v.x += bv.x; v.y += bv.y; v.z += bv.z; v.w += bv.w;
      }
      if (ACC) {
        float4 ov = *(const float4*)cp;
        v.x += ov.x; v.y += ov.y; v.z += ov.z; v.w += ov.w;
      }
      *(float4*)cp = v;
      if (W16) {
        *(short4*)(C16 + (size_t)row * ldc + col) =
            make_short4(f2bf(v.x), f2bf(v.y), f2bf(v.z), f2bf(v.w));
      }
      if (SYM) {
        if (m0 != n0) {       // off-diagonal tile: mirror store (bit-identical)
          float vv[4] = {v.x, v.y, v.z, v.w};
#pragma unroll
          for (int i = 0; i < 4; i++)
            Cb[(size_t)(col + i) * ldc + row] = vv[i];
        }
      }
    }
  }
}

// ---- transpose+cast: W[K][N] fp32 -> Wt[Np][K] bf16 (zero pad rows >= N) ----
__global__ void tcast_kernel(const float* __restrict__ W, short* __restrict__ Wt,
                             int K, int N)
{
  __shared__ float tile[32][33];
  int n0 = blockIdx.x * 32, k0 = blockIdx.y * 32;
  int c = threadIdx.x & 31, r8 = threadIdx.x >> 5;
#pragma unroll
  for (int i = 0; i < 4; i++) {
    int r = r8 + i * 8;
    int n = n0 + c;
    tile[r][c] = (n < N) ? W[(size_t)(k0 + r) * N + n] : 0.f;
  }
  __syncthreads();
#pragma unroll
  for (int i = 0; i < 4; i++) {
    int r = r8 + i * 8;
    Wt[(size_t)(n0 + r) * K + k0 + c] = f2bf(tile[c][r]);
  }
}

// ---- dual-dir variant: blockIdx.z selects source weight + dest offset ----
__global__ void tcast2_kernel(const float* __restrict__ W0, const float* __restrict__ W1,
                              short* __restrict__ Wt, int K, int N, long long sWt)
{
  __shared__ float tile[32][33];
  const int dir = blockIdx.z;
  const float* W = dir ? W1 : W0;
  short* Wtd = Wt + (size_t)dir * sWt;
  int n0 = blockIdx.x * 32, k0 = blockIdx.y * 32;
  int c = threadIdx.x & 31, r8 = threadIdx.x >> 5;
#pragma unroll
  for (int i = 0; i < 4; i++) {
    int r = r8 + i * 8;
    int n = n0 + c;
    tile[r][c] = (n < N) ? W[(size_t)(k0 + r) * N + n] : 0.f;
  }
  __syncthreads();
#pragma unroll
  for (int i = 0; i < 4; i++) {
    int r = r8 + i * 8;
    Wtd[(size_t)(n0 + r) * K + k0 + c] = f2bf(tile[c][r]);
  }
}

// ---- gather+cast: Ag16[m][s*256+d] = x[b][s][t][d], m=b*2048+t ----
__global__ void gather_cast_kernel(const float* __restrict__ x, short* __restrict__ Ag)
{
  int idx = blockIdx.x * 256 + threadIdx.x;
  int m = idx / 192;
  int g = idx - m * 192;
  int k = g * 4;
  int s = k >> 8, d = k & 255;
  int b = m >> 11, t = m & 2047;
  float4 v = *(const float4*)(x + ((size_t)((b * 3 + s) * 2048 + t) << 8) + d);
  *(short4*)(Ag + (size_t)m * 768 + k) = make_short4(f2bf(v.x), f2bf(v.y), f2bf(v.z), f2bf(v.w));
}

// ---------------- LayerNorm over 512, in place + bf16 copy ----------------
__global__ void ln512_kernel(float* __restrict__ xio, const float* __restrict__ g,
                             const float* __restrict__ b, short* __restrict__ o16)
{
  const int row = blockIdx.x;
  const int lane = threadIdx.x;
  float* xr = xio + (size_t)row * 512;
  float4 v0 = *(float4*)(xr + lane * 4);
  float4 v1 = *(float4*)(xr + 256 + lane * 4);
  float sum = v0.x + v0.y + v0.z + v0.w + v1.x + v1.y + v1.z + v1.w;
#pragma unroll
  for (int o = 32; o >= 1; o >>= 1) sum += __shfl_xor(sum, o);
  const float mu = sum * (1.f / 512.f);
  float d[8] = {v0.x - mu, v0.y - mu, v0.z - mu, v0.w - mu,
                v1.x - mu, v1.y - mu, v1.z - mu, v1.w - mu};
  float vs = 0.f;
#pragma unroll
  for (int i = 0; i < 8; i++) vs += d[i] * d[i];
#pragma unroll
  for (int o = 32; o >= 1; o >>= 1) vs += __shfl_xor(vs, o);
  const float inv = rsqrtf(vs * (1.f / 512.f) + 1e-5f);
  float4 g0 = *(const float4*)(g + lane * 4);
  float4 g1 = *(const float4*)(g + 256 + lane * 4);
  float4 b0 = *(const float4*)(b + lane * 4);
  float4 b1 = *(const float4*)(b + 256 + lane * 4);
  v0.x = d[0] * inv * g0.x + b0.x; v0.y = d[1] * inv * g0.y + b0.y;
  v0.z = d[2] * inv * g0.z + b0.z; v0.w = d[3] * inv * g0.w + b0.w;
  v1.x = d[4] * inv * g1.x + b1.x; v1.y = d[5] * inv * g1.y + b1.y;
  v1.z = d[6] * inv * g1.z + b1.z; v1.w = d[7] * inv * g1.w + b1.w;
  *(float4*)(xr + lane * 4) = v0;
  *(float4*)(xr + 256 + lane * 4) = v1;
  short* orow = o16 + (size_t)row * 512;
  *(short4*)(orow + lane * 4) = make_short4(f2bf(v0.x), f2bf(v0.y), f2bf(v0.z), f2bf(v0.w));
  *(short4*)(orow + 256 + lane * 4) = make_short4(f2bf(v1.x), f2bf(v1.y), f2bf(v1.z), f2bf(v1.w));
}

// --------- dt = softplus(raw + dtb), logdA = -dt * exp(Alog); dual-dir ---------
__global__ void dtprep_kernel(const float* __restrict__ Z,
                              const float* __restrict__ dtb0, const float* __restrict__ dtb1,
                              const float* __restrict__ Alog0, const float* __restrict__ Alog1,
                              float* __restrict__ dtv, float* __restrict__ ldA)
{
  const int dir = blockIdx.y;
  const float* Zd = Z + (size_t)dir * ZB_STRIDE;
  const float* dtb = dir ? dtb1 : dtb0;
  const float* Alog = dir ? Alog1 : Alog0;
  float* dtvd = dtv + dir * DT_STRIDE;
  float* ldAd = ldA + dir * DT_STRIDE;
  int idx = blockIdx.x * 256 + threadIdx.x;
  int row = idx >> 4, hh = idx & 15;
  float raw = Zd[(size_t)row * 2320 + 2304 + hh] + dtb[hh];
  float dt = raw > 20.f ? raw : log1pf(expf(raw));
  dtvd[idx] = dt;
  ldAd[idx] = -dt * expf(Alog[hh]);
}

// ---- depthwise conv(4) + bias + silu, bf16 out; dual-dir ----
// Sliding-window time tiling: every Z element fetched exactly once.
__global__ void conv_kernel(const float* __restrict__ Z,
                            const float* __restrict__ cw0, const float* __restrict__ cw1,
                            const float* __restrict__ cb0, const float* __restrict__ cb1,
                            short* __restrict__ xcv)
{
  const int dir = blockIdx.z;
  const int t0 = blockIdx.x * 64;
  const int b = blockIdx.y / 5;
  const int chb = blockIdx.y % 5;
  const int c = chb * 256 + threadIdx.x;
  const float* convw = dir ? cw1 : cw0;
  const float* convb = dir ? cb1 : cb0;
  const float* Zd = Z + (size_t)dir * ZB_STRIDE + (size_t)(b * 2048) * 2320 + 1024 + c;
  short* xd = xcv + (size_t)dir * XCV_STRIDE + (size_t)(b * 2048) * 1280 + c;

  const float w0 = convw[c * 4 + 0], w1 = convw[c * 4 + 1];
  const float w2 = convw[c * 4 + 2], w3 = convw[c * 4 + 3];
  const float bias = convb[c];
  const int o = dir ? 0 : -3;

  float rr[4];
#pragma unroll
  for (int j = 0; j < 4; j++) {
    int pos = t0 + o + j;
    rr[j] = (pos >= 0 && pos < 2048) ? Zd[(size_t)pos * 2320] : 0.f;
  }
#pragma unroll 8
  for (int i = 0; i < 64; i++) {
    float a = bias;
    if (dir) { a += w0 * rr[3]; a += w1 * rr[2]; a += w2 * rr[1]; a += w3 * rr[0]; }
    else     { a += w0 * rr[0]; a += w1 * rr[1]; a += w2 * rr[2]; a += w3 * rr[3]; }
    xd[(size_t)(t0 + i) * 1280] = f2bf(a * sigf(a));
    rr[0] = rr[1]; rr[1] = rr[2]; rr[2] = rr[3];
    int pos = t0 + i + 1 + o + 3;
    rr[3] = (pos >= 0 && pos < 2048) ? Zd[(size_t)pos * 2320] : 0.f;
  }
}

// ============ chunked SSD scan, Lc=64, 32 chunks; dual-dir via blockIdx.z ============
__global__ __launch_bounds__(256) void chunk_state_kernel(
    const short* __restrict__ xcv_, const float* __restrict__ dtv_,
    const float* __restrict__ ldA_, short* __restrict__ Sbuf_,
    float* __restrict__ Pbuf_)
{
  __shared__ float sw[64];
  __shared__ short sXT[64 * 74];    // [p][s]
  __shared__ short sBw[128 * 74];   // [n][s], weight folded
  const int dir = blockIdx.z;
  const short* xcv = xcv_ + (size_t)dir * XCV_STRIDE;
  const float* dtv = dtv_ + dir * DT_STRIDE;
  const float* ldA = ldA_ + dir * DT_STRIDE;
  short* Sbuf = Sbuf_ + (size_t)dir * SBUF_STRIDE;
  float* Pbuf = Pbuf_ + dir * PB_STRIDE;
  const int bh = blockIdx.x, ck = blockIdx.y;
  const int b = bh >> 4, h = bh & 15;
  const int tid = threadIdx.x;
  const int wave = tid >> 6, lane = tid & 63;

  if (tid < 64) {
    int tg = ck * 64 + tid;
    int tt = dir ? 2047 - tg : tg;
    size_t r = (size_t)(b * 2048 + tt) * 16 + h;
    float v = ldA[r];
#pragma unroll
    for (int o = 1; o < 64; o <<= 1) { float u = __shfl_up(v, o); if (tid >= o) v += u; }
    float tot = __shfl(v, 63);
    sw[tid] = __expf(tot - v) * dtv[r];
    if (tid == 63) Pbuf[bh * 32 + ck] = __expf(tot);
  }
  __syncthreads();
  for (int i4 = tid; i4 < 512; i4 += 256) {
    int s = i4 >> 3, p0 = (i4 & 7) * 8;
    int tg = ck * 64 + s; int tt = dir ? 2047 - tg : tg;
    bf16x8 xv = *(const bf16x8*)(xcv + (size_t)(b * 2048 + tt) * 1280 + h * 64 + p0);
#pragma unroll
    for (int j = 0; j < 8; j++) sXT[(p0 + j) * 74 + s] = xv[j];
  }
  for (int i4 = tid; i4 < 1024; i4 += 256) {
    int s = i4 >> 4, n0 = (i4 & 15) * 8;
    int tg = ck * 64 + s; int tt = dir ? 2047 - tg : tg;
    bf16x8 bv = *(const bf16x8*)(xcv + (size_t)(b * 2048 + tt) * 1280 + 1024 + n0);
    float w = sw[s];
#pragma unroll
    for (int j = 0; j < 8; j++) sBw[(n0 + j) * 74 + s] = f2bf(w * bf2f(bv[j]));
  }
  __syncthreads();

  const int mcol = lane & 15, kgrp = (lane >> 4) * 8;
  bf16x8 af[2];
#pragma unroll
  for (int kk = 0; kk < 2; kk++)
    af[kk] = *(bf16x8*)&sXT[(wave * 16 + mcol) * 74 + kk * 32 + kgrp];
  f32x4 acc[8] = {};
#pragma unroll
  for (int j = 0; j < 8; j++)
#pragma unroll
    for (int kk = 0; kk < 2; kk++) {
      bf16x8 bf = *(bf16x8*)&sBw[(j * 16 + mcol) * 74 + kk * 32 + kgrp];
      acc[j] = __builtin_amdgcn_mfma_f32_16x16x32_bf16(bf, af[kk], acc[j], 0, 0, 0);
    }
  short* Sp = Sbuf + ((size_t)(bh * 32 + ck) << 13);
  const int p = wave * 16 + mcol;
  const int nq = (lane >> 4) * 4;
#pragma unroll
  for (int j = 0; j < 8; j++) {
    *(short4*)(Sp + p * 128 + j * 16 + nq) = make_short4(
        f2bf(acc[j][0]), f2bf(acc[j][1]), f2bf(acc[j][2]), f2bf(acc[j][3]));
  }
}

// chunk_scan: in place on bf16 S, fp32 accumulate. 2 elems/thread; dual-dir.
__global__ void chunk_scan_kernel(short* __restrict__ Sbuf, const float* __restrict__ Pbuf)
{
  int idx = blockIdx.x * 256 + threadIdx.x;
  int bhd = idx >> 12;
  int pr = idx & 4095;
  int dir = bhd >> 6, bh = bhd & 63;
  short* Sb = Sbuf + (size_t)dir * SBUF_STRIDE;
  const float* Pb = Pbuf + dir * PB_STRIDE;
  float h0 = 0.f, h1 = 0.f;
  for (int ck = 0; ck < 32; ck++) {
    size_t off = ((size_t)(bh * 32 + ck) << 13) + pr * 2;
    unsigned int u = *(const unsigned int*)(Sb + off);
    float s0 = bf2f((short)(u & 0xffff));
    float s1 = bf2f((short)(u >> 16));
    float P = Pb[bh * 32 + ck];
    unsigned int w = (unsigned int)(unsigned short)f2bf(h0) |
                     ((unsigned int)(unsigned short)f2bf(h1) << 16);
    *(unsigned int*)(Sb + off) = w;
    h0 = P * h0 + s0;
    h1 = P * h1 + s1;
  }
}

// ======== chunk_out (MFMA): y = P@X + exp(L_t)*(C@H^T) + Dh*x, bf16 out; dual-dir ========
__global__ __launch_bounds__(256) void chunk_out_kernel(
    const short* __restrict__ xcv_, const float* __restrict__ dtv_,
    const float* __restrict__ ldA_, const short* __restrict__ Sbuf_,
    const float* __restrict__ Dh0, const float* __restrict__ Dh1,
    short* __restrict__ y_)
{
  extern __shared__ short smem16[];
  short* sB  = smem16;            // [64][136]
  short* sXT = sB + 64 * 136;     // [64][74]
  short* sP  = sXT + 64 * 74;     // [64][74]
  float* sL  = (float*)(sP + 64 * 74);
  float* sdt = sL + 64;

  const int dir = blockIdx.z;
  const short* xcv = xcv_ + (size_t)dir * XCV_STRIDE;
  const float* dtv = dtv_ + dir * DT_STRIDE;
  const float* ldA = ldA_ + dir * DT_STRIDE;
  const short* Sbuf = Sbuf_ + (size_t)dir * SBUF_STRIDE;
  const float* Dh = dir ? Dh1 : Dh0;
  short* y = y_ + (size_t)dir * YB_STRIDE;

  const int bh = blockIdx.x, ck = blockIdx.y;
  const int b = bh >> 4, h = bh & 15;
  const int tid = threadIdx.x;
  const int wave = tid >> 6, lane = tid & 63;

  const int mcol = lane & 15;
  const int kgrp = (lane >> 4) * 8;
  const int trow = wave * 16 + mcol;
  const int sq = (lane >> 4) * 4;

  const int tgc = ck * 64 + trow;
  const int ttc = dir ? 2047 - tgc : tgc;
  const short* crow = xcv + (size_t)(b * 2048 + ttc) * 1280 + 1152;
  bf16x8 afC[4];
#pragma unroll
  for (int kk = 0; kk < 4; kk++)
    afC[kk] = *(const bf16x8*)(crow + kk * 32 + kgrp);

  if (tid < 64) {
    int tg = ck * 64 + tid;
    int tt = dir ? 2047 - tg : tg;
    size_t r = (size_t)(b * 2048 + tt) * 16 + h;
    float v = ldA[r];
#pragma unroll
    for (int o = 1; o < 64; o <<= 1) { float u = __shfl_up(v, o); if (tid >= o) v += u; }
    sL[tid] = v;
    sdt[tid] = dtv[r];
  }
  for (int i4 = tid; i4 < 1024; i4 += 256) {
    int t = i4 >> 4, c8 = (i4 & 15) * 8;
    int tg = ck * 64 + t; int tt = dir ? 2047 - tg : tg;
    const short* rp = xcv + (size_t)(b * 2048 + tt) * 1280;
    *(bf16x8*)&sB[t * 136 + c8] = *(const bf16x8*)(rp + 1024 + c8);
  }
  for (int i4 = tid; i4 < 512; i4 += 256) {
    int t = i4 >> 3, p0 = (i4 & 7) * 8;
    int tg = ck * 64 + t; int tt = dir ? 2047 - tg : tg;
    bf16x8 xv = *(const bf16x8*)(xcv + (size_t)(b * 2048 + tt) * 1280 + h * 64 + p0);
#pragma unroll
    for (int j = 0; j < 8; j++) sXT[(p0 + j) * 74 + t] = xv[j];
  }
  __syncthreads();

  f32x4 sacc[4] = {};
#pragma unroll
  for (int j = 0; j < 4; j++)
#pragma unroll
    for (int kk = 0; kk < 4; kk++) {
      bf16x8 bf = *(bf16x8*)&sB[(j * 16 + mcol) * 136 + kk * 32 + kgrp];
      sacc[j] = __builtin_amdgcn_mfma_f32_16x16x32_bf16(bf, afC[kk], sacc[j], 0, 0, 0);
    }

  const float Lt = sL[trow];
#pragma unroll
  for (int j = 0; j < 4; j++) {
    int s0 = j * 16 + sq;
    float vr[4];
#pragma unroll
    for (int r = 0; r < 4; r++) {
      int s = s0 + r;
      vr[r] = (trow >= s) ? sacc[j][r] * __expf(Lt - sL[s]) * sdt[s] : 0.f;
    }
    *(short4*)&sP[trow * 74 + s0] = make_short4(
        f2bf(vr[0]), f2bf(vr[1]), f2bf(vr[2]), f2bf(vr[3]));
  }
  // sP rows are per-wave-disjoint: intra-wave LDS ordering suffices.
  asm volatile("s_waitcnt lgkmcnt(0)" ::: "memory");
  __builtin_amdgcn_sched_barrier(0);

  bf16x8 afP[2];
#pragma unroll
  for (int kk = 0; kk < 2; kk++)
    afP[kk] = *(bf16x8*)&sP[trow * 74 + kk * 32 + kgrp];
  f32x4 yacc[4] = {};
#pragma unroll
  for (int j = 0; j < 4; j++)
#pragma unroll
    for (int kk = 0; kk < 2; kk++) {
      bf16x8 bf = *(bf16x8*)&sXT[(j * 16 + mcol) * 74 + kk * 32 + kgrp];
      yacc[j] = __builtin_amdgcn_mfma_f32_16x16x32_bf16(bf, afP[kk], yacc[j], 0, 0, 0);
    }
  const short* Hp = Sbuf + ((size_t)(bh * 32 + ck) << 13);
  f32x4 y2[4] = {};
#pragma unroll
  for (int j = 0; j < 4; j++)
#pragma unroll
    for (int kk = 0; kk < 4; kk++) {
      bf16x8 bf = *(const bf16x8*)(Hp + (j * 16 + mcol) * 128 + kk * 32 + kgrp);
      y2[j] = __builtin_amdgcn_mfma_f32_16x16x32_bf16(bf, afC[kk], y2[j], 0, 0, 0);
    }

  const float dh = Dh[h];
  const float eL = __expf(Lt);
  short* yrow = y + (size_t)(b * 2048 + ttc) * 1024 + h * 64;
#pragma unroll
  for (int j = 0; j < 4; j++) {
    int p0 = j * 16 + sq;
    short o[4];
#pragma unroll
    for (int r = 0; r < 4; r++) {
      float xv = bf2f(sXT[(p0 + r) * 74 + trow]);
      o[r] = f2bf(yacc[j][r] + eL * y2[j][r] + dh * xv);
    }
    *(short4*)(yrow + p0) = make_short4(o[0], o[1], o[2], o[3]);
  }
}

// ------ y16 = bf16(rmsnorm(y16 * silu(z)) * normw), in place; dual-dir ------
__global__ void rms_kernel(short* __restrict__ y_, const float* __restrict__ Z,
                           const float* __restrict__ nw0, const float* __restrict__ nw1)
{
  const int dir = blockIdx.y;
  const int row = blockIdx.x;
  const int lane = threadIdx.x;
  short* yr = y_ + (size_t)dir * YB_STRIDE + (size_t)row * 1024;
  const float* zr = Z + (size_t)dir * ZB_STRIDE + (size_t)row * 2320;
  const float* normw = dir ? nw1 : nw0;
  float vals[16];
  float ss = 0.f;
#pragma unroll
  for (int jj = 0; jj < 4; jj++) {
    int off = jj * 256 + lane * 4;
    short4 yv = *(short4*)(yr + off);
    float4 zv = *(const float4*)(zr + off);
    float a0 = bf2f(yv.x) * (zv.x * sigf(zv.x));
    float a1 = bf2f(yv.y) * (zv.y * sigf(zv.y));
    float a2 = bf2f(yv.z) * (zv.z * sigf(zv.z));
    float a3 = bf2f(yv.w) * (zv.w * sigf(zv.w));
    vals[jj * 4 + 0] = a0; vals[jj * 4 + 1] = a1;
    vals[jj * 4 + 2] = a2; vals[jj * 4 + 3] = a3;
    ss += a0 * a0 + a1 * a1 + a2 * a2 + a3 * a3;
  }
#pragma unroll
  for (int o = 32; o >= 1; o >>= 1) ss += __shfl_xor(ss, o);
  const float scale = rsqrtf(ss * (1.f / 1024.f) + 1e-5f);
#pragma unroll
  for (int jj = 0; jj < 4; jj++) {
    int off = jj * 256 + lane * 4;
    float4 nw = *(const float4*)(normw + off);
    *(short4*)(yr + off) = make_short4(
        f2bf(vals[jj * 4 + 0] * scale * nw.x), f2bf(vals[jj * 4 + 1] * scale * nw.y),
        f2bf(vals[jj * 4 + 2] * scale * nw.z), f2bf(vals[jj * 4 + 3] * scale * nw.w));
  }
}

// ---- ob16 = bf16((od0+od1) * silu(h)) over 8192x512 ----
__global__ void combine_kernel(const float* __restrict__ od0, const float* __restrict__ od1,
                               const float* __restrict__ h, short* __restrict__ ob)
{
  size_t idx = (size_t)blockIdx.x * 256 + threadIdx.x;
  float4 a = ((const float4*)od0)[idx];
  float4 bb = ((const float4*)od1)[idx];
  float4 g = ((const float4*)h)[idx];
  float4 o;
  o.x = (a.x + bb.x) * (g.x * sigf(g.x));
  o.y = (a.y + bb.y) * (g.y * sigf(g.y));
  o.z = (a.z + bb.z) * (g.z * sigf(g.z));
  o.w = (a.w + bb.w) * (g.w * sigf(g.w));
  *(short4*)(ob + idx * 4) = make_short4(f2bf(o.x), f2bf(o.y), f2bf(o.z), f2bf(o.w));
}

__global__ void lnshort_kernel(const float* __restrict__ v, const float* __restrict__ g,
                               const float* __restrict__ b, const float* __restrict__ shortcut,
                               float* __restrict__ out0, short* __restrict__ fn)
{
  const int row = blockIdx.x;
  const int lane = threadIdx.x;
  size_t base = (size_t)row * 256;
  float4 x = *(const float4*)(v + base + lane * 4);
  float sum = x.x + x.y + x.z + x.w;
#pragma unroll
  for (int o = 32; o >= 1; o >>= 1) sum += __shfl_xor(sum, o);
  const float mu = sum * (1.f / 256.f);
  float d[4] = {x.x - mu, x.y - mu, x.z - mu, x.w - mu};
  float vs = d[0] * d[0] + d[1] * d[1] + d[2] * d[2] + d[3] * d[3];
#pragma unroll
  for (int o = 32; o >= 1; o >>= 1) vs += __shfl_xor(vs, o);
  const float inv = rsqrtf(vs * (1.f / 256.f) + 1e-5f);
  float4 gg = *(const float4*)(g + lane * 4);
  float4 bb = *(const float4*)(b + lane * 4);
  float4 sc = *(const float4*)(shortcut + base + lane * 4);
  float4 o4;
  o4.x = d[0] * inv * gg.x + bb.x + sc.x;
  o4.y = d[1] * inv * gg.y + bb.y + sc.y;
  o4.z = d[2] * inv * gg.z + bb.z + sc.z;
  o4.w = d[3] * inv * gg.w + bb.w + sc.w;
  *(float4*)(out0 + base + lane * 4) = o4;
  float ns = o4.x * o4.x + o4.y * o4.y + o4.z * o4.z + o4.w * o4.w;
#pragma unroll
  for (int o = 32; o >= 1; o >>= 1) ns += __shfl_xor(ns, o);
  const float r = 1.f / fmaxf(sqrtf(ns), 1e-12f);
  *(short4*)(fn + base + lane * 4) =
      make_short4(f2bf(o4.x * r), f2bf(o4.y * r), f2bf(o4.z * r), f2bf(o4.w * r));
}

extern "C" void kernel_launch(void* const* d_in, const int* in_sizes, int n_in,
                              void* d_out, int out_size, void* d_ws, size_t ws_size,
                              hipStream_t stream)
{
  (void)in_sizes; (void)n_in; (void)out_size; (void)ws_size;
  const float* x        = (const float*)d_in[0];
  const float* Wp       = (const float*)d_in[1];
  const float* bp       = (const float*)d_in[2];
  const float* Wpre     = (const float*)d_in[3];
  const float* bpre     = (const float*)d_in[4];
  const float* lnpre_g  = (const float*)d_in[5];
  const float* lnpre_b  = (const float*)d_in[6];
  const float* Wpost    = (const float*)d_in[7];
  const float* bpost    = (const float*)d_in[8];
  const float* lnpost_g = (const float*)d_in[9];
  const float* lnpost_b = (const float*)d_in[10];
  const float* Win_f   = (const float*)d_in[11];
  const float* convw_f = (const float*)d_in[12];
  const float* convb_f = (const float*)d_in[13];
  const float* dtb_f   = (const float*)d_in[14];
  const float* Alog_f  = (const float*)d_in[15];
  const float* Dh_f    = (const float*)d_in[16];
  const float* normw_f = (const float*)d_in[17];
  const float* Wout_f  = (const float*)d_in[18];
  const float* Win_b   = (const float*)d_in[19];
  const float* convw_b = (const float*)d_in[20];
  const float* convb_b = (const float*)d_in[21];
  const float* dtb_b   = (const float*)d_in[22];
  const float* Alog_b  = (const float*)d_in[23];
  const float* Dh_b    = (const float*)d_in[24];
  const float* normw_b = (const float*)d_in[25];
  const float* Wout_b  = (const float*)d_in[26];

  // ---- workspace layout (floats; 75,497,472 fl = 288 MiB available) ----
  float* ws   = (float*)d_ws;
  float* Zb   = ws;                         // 2 x 19,005,440
  float* xcvr = Zb + 2 * 19005440;          // 10,485,760 (overlay region)
  float* xc   = xcvr + 10485760;            // 2,097,152
  float* hbuf = xc + 2097152;               // 4,194,304
  short* hb16 = (short*)(hbuf + 4194304);   // 2,097,152 fl
  float* yb16f= hbuf + 4194304 + 2097152;   // 8,388,608 fl (2 dirs x 8192x1024 sh)
  short* yb16 = (short*)yb16f;
  float* odun = yb16f + 8388608;            // 4,194,304 (unused since r10; kept for layout)
  float* dtv  = odun + 4194304;             // 2 x 131,072
  float* ldA  = dtv + 262144;               // 2 x 131,072
  float* Pbuf = ldA + 262144;               // 2 x 2,048
  short* WinT = (short*)(Pbuf + 4096);      // 2 x 2560x512 sh = 1,310,720 fl (N-padded)
  short* WoutT= WinT + 2 * WINT_STRIDE;     // 2 x 512x1024 sh = 524,288 fl
  // end = 71,831,552 fl < 75,497,472 ok

  short* xcv16  = (short*)xcvr;                // 2 dirs x 8192x1280 sh (scan loop)
  short* Ag16   = (short*)xcvr;                // 8192x768 sh (until gather gemm)
  short* WpT    = (short*)(xcvr + 3145728);    // 256x768 sh
  short* xcb    = (short*)xcvr;                // 8192x256 sh (until pre gemm)
  short* WpreT  = (short*)(xcvr + 1048576);    // 512x256 sh
  short* ob16   = (short*)xcvr;                // 8192x512 sh (after xcv dead)
  short* WpostT = (short*)(xcvr + 2097152);    // 256x512 sh (past ob16)
  float* vbuf = yb16f;                         // after Wout gemms (yb16 dead)
  short* fn16 = (short*)(yb16f + 2097152);

  float* out0 = (float*)d_out;
  float* attn = out0 + 2097152;
  short* Sbuf16 = (short*)attn;                // 2 dirs x 64*32*8192 sh (dead before Wout)
  // After rms, the Zb region (38M fl) is DEAD -> both Wout outputs live there
  // at a constant stride so one batched dispatch covers both dirs.
  float* odb = Zb;                             // [2][8192x512] fp32, stride 4,194,304

  // ---- prologue ----
  tcast_kernel<<<dim3(8, 24), 256, 0, stream>>>(Wp, WpT, 768, 256);
  gather_cast_kernel<<<6144, 256, 0, stream>>>(x, Ag16);
  // Wp gemm writes fp32 xc (shortcut) AND bf16 xcb (fused cast)
  gemm16_kernel<true, false, true, false><<<dim3(64, 2), 256, 0, stream>>>(
      Ag16, WpT, bp, xc, 8192, 256, 768, 256, 0, 0, 0, xcb);
  tcast_kernel<<<dim3(16, 8), 256, 0, stream>>>(Wpre, WpreT, 256, 512);
  gemm16_kernel<true, false, false, false><<<dim3(64, 4), 256, 0, stream>>>(
      xcb, WpreT, bpre, hbuf, 8192, 512, 256, 512, 0, 0, 0, nullptr);
  ln512_kernel<<<8192, 64, 0, stream>>>(hbuf, lnpre_g, lnpre_b, hb16);

  // ---- both directions batched (blockIdx.z / blockIdx.y = dir) ----
  tcast2_kernel<<<dim3(80, 16, 2), 256, 0, stream>>>(Win_f, Win_b, WinT, 512, 2320, WINT_STRIDE);
  tcast2_kernel<<<dim3(16, 32, 2), 256, 0, stream>>>(Wout_f, Wout_b, WoutT, 1024, 512, 524288);
  gemm16_kernel<false, false, false, false><<<dim3(64, 19, 2), 256, 0, stream>>>(
      hb16, WinT, nullptr, Zb, 8192, 2320, 512, 2320, 0, WINT_STRIDE, ZB_STRIDE, nullptr);
  dtprep_kernel<<<dim3(512, 2), 256, 0, stream>>>(Zb, dtb_f, dtb_b, Alog_f, Alog_b, dtv, ldA);
  conv_kernel<<<dim3(32, 20, 2), 256, 0, stream>>>(Zb, convw_f, convw_b, convb_f, convb_b, xcv16);
  chunk_state_kernel<<<dim3(64, 32, 2), 256, 0, stream>>>(xcv16, dtv, ldA, Sbuf16, Pbuf);
  chunk_scan_kernel<<<2048, 256, 0, stream>>>(Sbuf16, Pbuf);
  chunk_out_kernel<<<dim3(64, 32, 2), 256, 36864, stream>>>(xcv16, dtv, ldA, Sbuf16, Dh_f, Dh_b, yb16);
  rms_kernel<<<dim3(8192, 2), 64, 0, stream>>>(yb16, Zb, normw_f, normw_b);
  // both Wout gemms in ONE batched dispatch (Zb dead after rms -> odb overlay)
  gemm16_kernel<false, false, false, false><<<dim3(64, 4, 2), 256, 0, stream>>>(
      yb16, WoutT, nullptr, odb, 8192, 512, 1024, 512,
      YB_STRIDE, 524288, 4194304, nullptr);

  // ---- epilogue ----
  combine_kernel<<<4096, 256, 0, stream>>>(odb, odb + 4194304, hbuf, ob16);
  tcast_kernel<<<dim3(8, 16), 256, 0, stream>>>(Wpost, WpostT, 512, 256);
  gemm16_kernel<true, false, false, false><<<dim3(64, 2), 256, 0, stream>>>(
      ob16, WpostT, bpost, vbuf, 8192, 256, 512, 256, 0, 0, 0, nullptr);
  lnshort_kernel<<<8192, 64, 0, stream>>>(vbuf, lnpost_g, lnpost_b, xc, out0, fn16);
  // attn = fn @ fn^T is SYMMETRIC: compute 136 upper-triangle tiles (of 256),
  // mirror-store off-diagonal tiles (bit-identical fp32 values).
  gemm16_kernel<false, false, false, true><<<dim3(136, 1, 4), 256, 0, stream>>>(
      fn16, fn16, nullptr, attn, 2048, 2048, 256, 2048,
      (long long)2048 * 256, (long long)2048 * 256, (long long)2048 * 2048, nullptr);
}